// Round 7
// baseline (1093.036 us; speedup 1.0000x reference)
//
#include <hip/hip_runtime.h>
#include <cstddef>
#include <cstdint>

#define N_NODES 100000
#define N_EDGES 3200000
#define D 256
#define SCAN_BLOCKS ((N_NODES + 1023) / 1024)  // 98
#define BSHIFT 9                                // 512 rows per bucket
#define NBUCK ((N_NODES + (1 << BSHIFT) - 1) >> BSHIFT)  // 196
#define EPB 4096                                // edges per pass-1 block

typedef __attribute__((ext_vector_type(8))) short bf16x8;
typedef __attribute__((ext_vector_type(4))) float f32x4;
typedef unsigned int u32;
typedef unsigned long long u64;
typedef __attribute__((ext_vector_type(4))) unsigned int u32x4;

#define GLOAD16(gsrc, ldst)                                                      \
    __builtin_amdgcn_global_load_lds(                                            \
        (const __attribute__((address_space(1))) void*)(gsrc),                   \
        (__attribute__((address_space(3))) void*)(ldst), 16, 0, 0)

__device__ __forceinline__ u32 ntload_u32(const void* p) {
    return __builtin_nontemporal_load((const u32*)p);
}
__device__ __forceinline__ u64 ntload_u64(const void* p) {
    return __builtin_nontemporal_load((const u64*)p);
}
__device__ __forceinline__ u32x4 ntload_u128(const void* p) {
    return __builtin_nontemporal_load((const u32x4*)p);
}
__device__ __forceinline__ void ntstore_u32(void* p, u32 v) {
    __builtin_nontemporal_store(v, (u32*)p);
}
__device__ __forceinline__ void ntstore_u64(void* p, u64 v) {
    __builtin_nontemporal_store(v, (u64*)p);
}

__device__ __forceinline__ ushort f2b(float f) {  // f32 -> bf16 RNE
    unsigned u = __float_as_uint(f);
    return (ushort)((u + 0x7fffu + ((u >> 16) & 1u)) >> 16);
}

// ---------------- degree histogram ----------------
__global__ __launch_bounds__(256) void hist_kernel(const int* __restrict__ row,
                                                   int* __restrict__ deg) {
    int e = blockIdx.x * 256 + threadIdx.x;
    if (e < N_EDGES) atomicAdd(&deg[(int)ntload_u32(&row[e])], 1);
}

// ---------------- scan stage A ----------------
__global__ __launch_bounds__(1024) void scanA_kernel(const int* __restrict__ deg,
                                                     int* __restrict__ rowptr,
                                                     int* __restrict__ blocksum) {
    __shared__ int waveTot[16];
    __shared__ int waveOff[16];
    const int tid  = threadIdx.x;
    const int lane = tid & 63;
    const int wv   = tid >> 6;
    const int idx  = blockIdx.x * 1024 + tid;
    int v = (idx < N_NODES) ? deg[idx] : 0;
    int inc = v;
#pragma unroll
    for (int off = 1; off < 64; off <<= 1) {
        int up = __shfl_up(inc, off, 64);
        if (lane >= off) inc += up;
    }
    if (lane == 63) waveTot[wv] = inc;
    __syncthreads();
    if (tid == 0) {
        int run = 0;
#pragma unroll
        for (int w = 0; w < 16; ++w) { waveOff[w] = run; run += waveTot[w]; }
        blocksum[blockIdx.x] = run;
    }
    __syncthreads();
    if (idx < N_NODES) rowptr[idx] = waveOff[wv] + (inc - v);
}

// ---------------- scan stage B ----------------
__global__ void scanB_kernel(int* __restrict__ blocksum, int* __restrict__ rowptr) {
    if (threadIdx.x == 0 && blockIdx.x == 0) {
        int run = 0;
        for (int b = 0; b < SCAN_BLOCKS; ++b) {
            int t = blocksum[b];
            blocksum[b] = run;
            run += t;
        }
        rowptr[N_NODES] = run;
    }
}

// ---------------- scan stage C ----------------
__global__ __launch_bounds__(1024) void scanC_kernel(int* __restrict__ rowptr,
                                                     const int* __restrict__ blocksum,
                                                     int* __restrict__ cursor) {
    const int idx = blockIdx.x * 1024 + threadIdx.x;
    if (idx < N_NODES) {
        int v = rowptr[idx] + blocksum[blockIdx.x];
        rowptr[idx] = v;
        cursor[idx] = v;
    }
}

// ---------------- bucket cursor init ----------------
__global__ void bucketinit_kernel(const int* __restrict__ rowptr,
                                  int* __restrict__ bucket_cursor) {
    int b = blockIdx.x * 256 + threadIdx.x;
    if (b < NBUCK) bucket_cursor[b] = rowptr[b << BSHIFT];
}

// ---------------- binned scatter pass 1 ----------------
__global__ __launch_bounds__(256) void binpass1_kernel(const int* __restrict__ erow,
                                                       const int* __restrict__ ecol,
                                                       const float* __restrict__ evalv,
                                                       int* __restrict__ bucket_cursor,
                                                       int* __restrict__ srow,
                                                       int2* __restrict__ scolval) {
    __shared__ int cnt[NBUCK];
    __shared__ int lstart[NBUCK];
    __shared__ int gbase[NBUCK];
    __shared__ int wtot[4];
    __shared__ int woff[4];
    __shared__ int   lrow[EPB];   // 16 KB
    __shared__ int2  lcv[EPB];    // 32 KB
    const int tid = threadIdx.x;
    const size_t base = (size_t)blockIdx.x * EPB;
    for (int b = tid; b < NBUCK; b += 256) cnt[b] = 0;
    __syncthreads();
    int rows[16];
    int2 cv[16];
    int loff[16];
#pragma unroll
    for (int i = 0; i < 16; ++i) {
        size_t e = base + (size_t)i * 256 + tid;
        if (e < N_EDGES) {
            int r = (int)ntload_u32(&erow[e]);
            rows[i] = r;
            cv[i] = make_int2((int)ntload_u32(&ecol[e]), (int)ntload_u32(&evalv[e]));
            loff[i] = atomicAdd(&cnt[r >> BSHIFT], 1);
        } else {
            rows[i] = -1;
        }
    }
    __syncthreads();
    {
        int b = tid;
        int v = (b < NBUCK) ? cnt[b] : 0;
        int lane = tid & 63, wv = tid >> 6;
        int inc = v;
#pragma unroll
        for (int off = 1; off < 64; off <<= 1) {
            int u = __shfl_up(inc, off, 64);
            if (lane >= off) inc += u;
        }
        if (lane == 63) wtot[wv] = inc;
        __syncthreads();
        if (tid == 0) {
            int run = 0;
#pragma unroll
            for (int w = 0; w < 4; ++w) { woff[w] = run; run += wtot[w]; }
        }
        __syncthreads();
        int exc = woff[wv] + inc - v;
        if (b < NBUCK) {
            lstart[b] = exc;
            if (v > 0) gbase[b] = atomicAdd(&bucket_cursor[b], v);
        }
    }
    __syncthreads();
#pragma unroll
    for (int i = 0; i < 16; ++i) {
        if (rows[i] >= 0) {
            int b = rows[i] >> BSHIFT;
            int p = lstart[b] + loff[i];
            lrow[p] = rows[i];
            lcv[p]  = cv[i];
        }
    }
    __syncthreads();
    const int total = lstart[NBUCK - 1] + cnt[NBUCK - 1];
    for (int p = tid; p < total; p += 256) {
        int r = lrow[p];
        int b = r >> BSHIFT;
        int g = gbase[b] + (p - lstart[b]);
        int2 c = lcv[p];
        ntstore_u32(&srow[g], (u32)r);
        ntstore_u64(&scolval[g], (u32)c.x | ((u64)(u32)c.y << 32));
    }
}

// ---------------- binned scatter pass 2 ----------------
__global__ __launch_bounds__(256) void binpass2_kernel(const int* __restrict__ rowptr,
                                                       const int* __restrict__ srow,
                                                       const int2* __restrict__ scolval,
                                                       int* __restrict__ cursor,
                                                       int2* __restrict__ cedge) {
    const int b = blockIdx.x;
    const int lo = rowptr[b << BSHIFT];
    const int rhiidx = ((b + 1) << BSHIFT);
    const int hi = rowptr[rhiidx > N_NODES ? N_NODES : rhiidx];
    for (int k = lo + threadIdx.x; k < hi; k += 256) {
        int r = (int)ntload_u32(&srow[k]);
        u64 cv = ntload_u64(&scolval[k]);
        int pos = atomicAdd(&cursor[r], 1);
        ntstore_u64(&cedge[pos], cv);
    }
}

// ---------------- f32 -> bf16 elementwise ----------------
__global__ __launch_bounds__(256) void cvt_kernel(const float* __restrict__ in,
                                                  ushort* __restrict__ out, int n4) {
    int i = blockIdx.x * 256 + threadIdx.x;
    if (i < n4) {
        u32x4 v = ntload_u128(&((const u32x4*)in)[i]);
        uint2 p;
        p.x = (unsigned)f2b(__uint_as_float(v.x)) | ((unsigned)f2b(__uint_as_float(v.y)) << 16);
        p.y = (unsigned)f2b(__uint_as_float(v.z)) | ((unsigned)f2b(__uint_as_float(v.w)) << 16);
        ((uint2*)out)[i] = p;  // cached: consumed by spmm/gemm next
    }
}

// ---------------- W [512][256] f32 -> Wt [256][512] bf16 (transpose) ----------------
__global__ __launch_bounds__(256) void wtrans_kernel(const float* __restrict__ W,
                                                     ushort* __restrict__ Wt) {
    int t = blockIdx.x * 256 + threadIdx.x;
    int j = t & 255;
    int k = t >> 8;
    Wt[(size_t)j * 512 + k] = f2b(W[(size_t)k * 256 + j]);
}

// ---------------- CSR SpMM (bf16 features): one wave per node ----------------
// cedge loads + out stores are non-temporal (streaming); h gather stays cached
// (each h row reused ~32x -> want L3 residency).
__global__ __launch_bounds__(256) void spmm_kernel(const int* __restrict__ rowptr,
                                                   const int2* __restrict__ cedge,
                                                   const ushort* __restrict__ h,
                                                   ushort* __restrict__ outb) {
    const int node = (blockIdx.x << 2) + (threadIdx.x >> 6);
    const int lane = threadIdx.x & 63;
    const uint2* __restrict__ h2 = (const uint2*)h;
    int k = rowptr[node];
    const int end = rowptr[node + 1];
    float a0 = 0.f, a1 = 0.f, a2 = 0.f, a3 = 0.f;
#define EDGE_FMA(ev, d)                                             \
    {                                                               \
        float v = __uint_as_float((u32)((ev) >> 32));               \
        a0 = fmaf(v, __uint_as_float((d).x << 16), a0);             \
        a1 = fmaf(v, __uint_as_float((d).x & 0xffff0000u), a1);     \
        a2 = fmaf(v, __uint_as_float((d).y << 16), a2);             \
        a3 = fmaf(v, __uint_as_float((d).y & 0xffff0000u), a3);     \
    }
    for (; k + 8 <= end; k += 8) {
        u64 e[8];
#pragma unroll
        for (int i = 0; i < 8; ++i) e[i] = ntload_u64(&cedge[k + i]);
        uint2 d[8];
#pragma unroll
        for (int i = 0; i < 8; ++i) d[i] = h2[(size_t)(u32)e[i] * 64 + lane];
#pragma unroll
        for (int i = 0; i < 8; ++i) EDGE_FMA(e[i], d[i])
    }
    for (; k < end; ++k) {
        u64 e = ntload_u64(&cedge[k]);
        uint2 d = h2[(size_t)(u32)e * 64 + lane];
        EDGE_FMA(e, d)
    }
#undef EDGE_FMA
    uint2 p;
    p.x = (unsigned)f2b(a0) | ((unsigned)f2b(a1) << 16);
    p.y = (unsigned)f2b(a2) | ((unsigned)f2b(a3) << 16);
    ntstore_u64(&((uint2*)outb)[(size_t)node * 64 + lane],
                (u64)p.x | ((u64)p.y << 32));
}

// ---------------- MFMA concat-GEMM, LDS-staged (m97 2-barrier structure) ----------
template <bool OUT_BF16>
__global__ __launch_bounds__(256, 2) void gemm_mfma_kernel(const ushort* __restrict__ A1,
                                                           const ushort* __restrict__ A2,
                                                           const ushort* __restrict__ Wt,
                                                           const float* __restrict__ bias,
                                                           void* __restrict__ outp) {
    __shared__ __align__(16) char lds[40960];  // As 0..8191, Bs 8192..40959
    const int tid  = threadIdx.x;
    const int wid  = tid >> 6;
    const int lane = tid & 63;
    const int lr   = lane & 15;
    const int g    = lane >> 4;
    const int bm   = blockIdx.x * 64;

    const int l3  = lane >> 3;                 // 0..7 (row within 8-row slot)
    const int cL  = ((lane & 7) ^ l3) * 8;     // logical 8-elem chunk for this slot
    int rowA[2];
#pragma unroll
    for (int p = 0; p < 2; ++p) {
        int r = (p * 4 + wid) * 8 + l3;        // 0..63
        int gr = bm + r;
        rowA[p] = gr < N_NODES ? gr : N_NODES - 1;
    }
    const ushort* wB = Wt + ((size_t)(wid * 8 + l3) << 9) + cL;  // + p*16384 + t*64

    int aoffs[4], boffs[4];
#pragma unroll
    for (int f = 0; f < 4; ++f) {
        aoffs[f] = (((f * 16 + lr) * 128 + g * 16) ^ ((lr & 7) << 4));
        boffs[f] = 8192 + (((wid * 64 + f * 16 + lr) * 128 + g * 16) ^ ((lr & 7) << 4));
    }

    f32x4 acc[4][4];
#pragma unroll
    for (int i = 0; i < 4; ++i)
#pragma unroll
        for (int j = 0; j < 4; ++j) acc[i][j] = (f32x4){0.f, 0.f, 0.f, 0.f};

#pragma unroll 1
    for (int t = 0; t < 8; ++t) {
        const ushort* __restrict__ Ab = (t < 4) ? A1 : A2;
        const int k0 = (t & 3) * 64;
#pragma unroll
        for (int p = 0; p < 2; ++p)
            GLOAD16(Ab + (size_t)rowA[p] * 256 + k0 + cL, lds + (p * 4 + wid) * 1024);
#pragma unroll
        for (int p = 0; p < 8; ++p)
            GLOAD16(wB + p * 16384 + t * 64, lds + 8192 + (p * 4 + wid) * 1024);
        __syncthreads();
#pragma unroll
        for (int kk = 0; kk < 2; ++kk) {
            const int kx = kk << 6;  // advance k-half by XOR (bit 6), not add
            bf16x8 bfr[4];
#pragma unroll
            for (int fc = 0; fc < 4; ++fc)
                bfr[fc] = *(const bf16x8*)(lds + (boffs[fc] ^ kx));
#pragma unroll
            for (int fr = 0; fr < 4; ++fr) {
                bf16x8 af = *(const bf16x8*)(lds + (aoffs[fr] ^ kx));
#pragma unroll
                for (int fc = 0; fc < 4; ++fc)
                    acc[fr][fc] = __builtin_amdgcn_mfma_f32_16x16x32_bf16(af, bfr[fc],
                                                                          acc[fr][fc], 0, 0, 0);
            }
        }
        __syncthreads();
    }

    float bv[4];
#pragma unroll
    for (int fc = 0; fc < 4; ++fc) bv[fc] = bias[wid * 64 + fc * 16 + lr];

    if (!OUT_BF16) {
        float* out = (float*)outp;
#pragma unroll
        for (int fr = 0; fr < 4; ++fr)
#pragma unroll
            for (int reg = 0; reg < 4; ++reg) {
                int row = bm + fr * 16 + g * 4 + reg;
                if (row < N_NODES) {
#pragma unroll
                    for (int fc = 0; fc < 4; ++fc)
                        out[(size_t)row * 256 + wid * 64 + fc * 16 + lr] =
                            acc[fr][fc][reg] + bv[fc];
                }
            }
    } else {
        ushort* out = (ushort*)outp;
        float (*L)[260] = (float(*)[260])lds;
#pragma unroll 1
        for (int half = 0; half < 2; ++half) {
            __syncthreads();
#pragma unroll
            for (int fr2 = 0; fr2 < 2; ++fr2) {
                int fr = half * 2 + fr2;
#pragma unroll
                for (int fc = 0; fc < 4; ++fc)
#pragma unroll
                    for (int reg = 0; reg < 4; ++reg) {
                        int r = fr2 * 16 + g * 4 + reg;
                        L[r][wid * 64 + fc * 16 + lr] = fmaxf(acc[fr][fc][reg] + bv[fc], 0.f);
                    }
            }
            __syncthreads();
            int r  = tid >> 3;
            int ch = tid & 7;
            int grow = bm + half * 32 + r;
            if (grow < N_NODES) {
#pragma unroll
                for (int q = 0; q < 4; ++q) {
                    float4 u0 = *(const float4*)&L[r][ch * 32 + q * 8];
                    float4 u1 = *(const float4*)&L[r][ch * 32 + q * 8 + 4];
                    uint2 pk;
                    pk.x = (unsigned)f2b(u0.x) | ((unsigned)f2b(u0.y) << 16);
                    pk.y = (unsigned)f2b(u0.z) | ((unsigned)f2b(u0.w) << 16);
                    uint2 pk2;
                    pk2.x = (unsigned)f2b(u1.x) | ((unsigned)f2b(u1.y) << 16);
                    pk2.y = (unsigned)f2b(u1.z) | ((unsigned)f2b(u1.w) << 16);
                    uint4 w4 = make_uint4(pk.x, pk.y, pk2.x, pk2.y);
                    *(uint4*)&out[(size_t)grow * 256 + ch * 32 + q * 8] = w4;
                }
            }
        }
    }
}

extern "C" void kernel_launch(void* const* d_in, const int* in_sizes, int n_in,
                              void* d_out, int out_size, void* d_ws, size_t ws_size,
                              hipStream_t stream) {
    const float* x     = (const float*)d_in[0];
    const int*   erow  = (const int*)d_in[1];
    const int*   ecol  = (const int*)d_in[2];
    const float* evalv = (const float*)d_in[3];
    const float* W1    = (const float*)d_in[4];
    const float* b1    = (const float*)d_in[5];
    const float* Wout  = (const float*)d_in[6];
    const float* bout  = (const float*)d_in[7];
    float* out = (float*)d_out;

    char* ws = (char*)d_ws;
    size_t off = 0;
    auto alloc = [&](size_t bytes) -> void* {
        void* p = ws + off;
        off += (bytes + 255) & ~(size_t)255;
        return p;
    };
    ushort* xb       = (ushort*)alloc((size_t)N_NODES * D * 2);     // 51.2 MB
    ushort* h1b      = (ushort*)alloc((size_t)N_NODES * D * 2);     // 51.2 MB
    ushort* neighb   = (ushort*)alloc((size_t)N_NODES * D * 2);     // 51.2 MB
    ushort* W1t      = (ushort*)alloc((size_t)512 * 256 * 2);
    ushort* Woutt    = (ushort*)alloc((size_t)512 * 256 * 2);
    int*    rowptr   = (int*)alloc((size_t)(N_NODES + 1) * sizeof(int));
    int*    deg      = (int*)alloc((size_t)N_NODES * sizeof(int));
    int*    cursor   = (int*)alloc((size_t)N_NODES * sizeof(int));
    int*    blocksum = (int*)alloc((size_t)SCAN_BLOCKS * sizeof(int));
    int*    bcursor  = (int*)alloc((size_t)NBUCK * sizeof(int));
    int*    srow     = (int*)alloc((size_t)N_EDGES * sizeof(int));      // 12.8 MB
    int2*   scolval  = (int2*)alloc((size_t)N_EDGES * sizeof(int2));    // 25.6 MB
    int2*   cedge    = (int2*)alloc((size_t)N_EDGES * sizeof(int2));    // 25.6 MB

    // 1. build CSR first (its streams are nt; won't pollute L3 for later stages)
    hipMemsetAsync(deg, 0, (size_t)N_NODES * sizeof(int), stream);
    hist_kernel<<<(N_EDGES + 255) / 256, 256, 0, stream>>>(erow, deg);
    scanA_kernel<<<SCAN_BLOCKS, 1024, 0, stream>>>(deg, rowptr, blocksum);
    scanB_kernel<<<1, 64, 0, stream>>>(blocksum, rowptr);
    scanC_kernel<<<SCAN_BLOCKS, 1024, 0, stream>>>(rowptr, blocksum, cursor);
    bucketinit_kernel<<<1, 256, 0, stream>>>(rowptr, bcursor);
    binpass1_kernel<<<(N_EDGES + EPB - 1) / EPB, 256, 0, stream>>>(erow, ecol, evalv,
                                                                   bcursor, srow, scolval);
    binpass2_kernel<<<NBUCK, 256, 0, stream>>>(rowptr, srow, scolval, cursor, cedge);

    // 2. converts right before first use (xb stays L3-resident for spmm1's gather)
    cvt_kernel<<<(N_NODES * D / 4 + 255) / 256, 256, 0, stream>>>(x, xb, N_NODES * D / 4);
    wtrans_kernel<<<512, 256, 0, stream>>>(W1, W1t);
    wtrans_kernel<<<512, 256, 0, stream>>>(Wout, Woutt);

    const int gblocks = (N_NODES + 63) / 64;  // 1563
    // layer 1
    spmm_kernel<<<N_NODES / 4, 256, 0, stream>>>(rowptr, cedge, xb, neighb);
    gemm_mfma_kernel<true><<<gblocks, 256, 0, stream>>>(xb, neighb, W1t, b1, h1b);
    // layer 2
    spmm_kernel<<<N_NODES / 4, 256, 0, stream>>>(rowptr, cedge, h1b, neighb);
    gemm_mfma_kernel<false><<<gblocks, 256, 0, stream>>>(h1b, neighb, Woutt, bout, out);
}

// Round 8
// 993.641 us; speedup vs baseline: 1.1000x; 1.1000x over previous
//
#include <hip/hip_runtime.h>
#include <cstddef>
#include <cstdint>

#define N_NODES 100000
#define N_EDGES 3200000
#define D 256
#define SCAN_BLOCKS ((N_NODES + 1023) / 1024)  // 98
#define BSHIFT 9                                // 512 rows per bucket
#define NBUCK ((N_NODES + (1 << BSHIFT) - 1) >> BSHIFT)  // 196
#define EPB 4096                                // edges per pass-1 block

typedef __attribute__((ext_vector_type(8))) short bf16x8;
typedef __attribute__((ext_vector_type(4))) float f32x4;
typedef unsigned int u32;
typedef unsigned long long u64;

#define GLOAD16(gsrc, ldst)                                                      \
    __builtin_amdgcn_global_load_lds(                                            \
        (const __attribute__((address_space(1))) void*)(gsrc),                   \
        (__attribute__((address_space(3))) void*)(ldst), 16, 0, 0)

__device__ __forceinline__ ushort f2b(float f) {  // f32 -> bf16 RNE
    unsigned u = __float_as_uint(f);
    return (ushort)((u + 0x7fffu + ((u >> 16) & 1u)) >> 16);
}

// ---------------- degree histogram ----------------
__global__ __launch_bounds__(256) void hist_kernel(const int* __restrict__ row,
                                                   int* __restrict__ deg) {
    int e = blockIdx.x * 256 + threadIdx.x;
    if (e < N_EDGES) atomicAdd(&deg[row[e]], 1);
}

// ---------------- scan stage A ----------------
__global__ __launch_bounds__(1024) void scanA_kernel(const int* __restrict__ deg,
                                                     int* __restrict__ rowptr,
                                                     int* __restrict__ blocksum) {
    __shared__ int waveTot[16];
    __shared__ int waveOff[16];
    const int tid  = threadIdx.x;
    const int lane = tid & 63;
    const int wv   = tid >> 6;
    const int idx  = blockIdx.x * 1024 + tid;
    int v = (idx < N_NODES) ? deg[idx] : 0;
    int inc = v;
#pragma unroll
    for (int off = 1; off < 64; off <<= 1) {
        int up = __shfl_up(inc, off, 64);
        if (lane >= off) inc += up;
    }
    if (lane == 63) waveTot[wv] = inc;
    __syncthreads();
    if (tid == 0) {
        int run = 0;
#pragma unroll
        for (int w = 0; w < 16; ++w) { waveOff[w] = run; run += waveTot[w]; }
        blocksum[blockIdx.x] = run;
    }
    __syncthreads();
    if (idx < N_NODES) rowptr[idx] = waveOff[wv] + (inc - v);
}

// ---------------- scan stage B ----------------
__global__ void scanB_kernel(int* __restrict__ blocksum, int* __restrict__ rowptr) {
    if (threadIdx.x == 0 && blockIdx.x == 0) {
        int run = 0;
        for (int b = 0; b < SCAN_BLOCKS; ++b) {
            int t = blocksum[b];
            blocksum[b] = run;
            run += t;
        }
        rowptr[N_NODES] = run;
    }
}

// ---------------- scan stage C ----------------
__global__ __launch_bounds__(1024) void scanC_kernel(int* __restrict__ rowptr,
                                                     const int* __restrict__ blocksum,
                                                     int* __restrict__ cursor) {
    const int idx = blockIdx.x * 1024 + threadIdx.x;
    if (idx < N_NODES) {
        int v = rowptr[idx] + blocksum[blockIdx.x];
        rowptr[idx] = v;
        cursor[idx] = v;
    }
}

// ---------------- bucket cursor init ----------------
__global__ void bucketinit_kernel(const int* __restrict__ rowptr,
                                  int* __restrict__ bucket_cursor) {
    int b = blockIdx.x * 256 + threadIdx.x;
    if (b < NBUCK) bucket_cursor[b] = rowptr[b << BSHIFT];
}

// ---------------- binned scatter pass 1 ----------------
__global__ __launch_bounds__(256) void binpass1_kernel(const int* __restrict__ erow,
                                                       const int* __restrict__ ecol,
                                                       const float* __restrict__ evalv,
                                                       int* __restrict__ bucket_cursor,
                                                       int* __restrict__ srow,
                                                       int2* __restrict__ scolval) {
    __shared__ int cnt[NBUCK];
    __shared__ int lstart[NBUCK];
    __shared__ int gbase[NBUCK];
    __shared__ int wtot[4];
    __shared__ int woff[4];
    __shared__ int   lrow[EPB];   // 16 KB
    __shared__ int2  lcv[EPB];    // 32 KB
    const int tid = threadIdx.x;
    const size_t base = (size_t)blockIdx.x * EPB;
    for (int b = tid; b < NBUCK; b += 256) cnt[b] = 0;
    __syncthreads();
    int rows[16];
    int2 cv[16];
    int loff[16];
#pragma unroll
    for (int i = 0; i < 16; ++i) {
        size_t e = base + (size_t)i * 256 + tid;
        if (e < N_EDGES) {
            int r = erow[e];
            rows[i] = r;
            cv[i] = make_int2(ecol[e], __float_as_int(evalv[e]));
            loff[i] = atomicAdd(&cnt[r >> BSHIFT], 1);
        } else {
            rows[i] = -1;
        }
    }
    __syncthreads();
    {
        int b = tid;
        int v = (b < NBUCK) ? cnt[b] : 0;
        int lane = tid & 63, wv = tid >> 6;
        int inc = v;
#pragma unroll
        for (int off = 1; off < 64; off <<= 1) {
            int u = __shfl_up(inc, off, 64);
            if (lane >= off) inc += u;
        }
        if (lane == 63) wtot[wv] = inc;
        __syncthreads();
        if (tid == 0) {
            int run = 0;
#pragma unroll
            for (int w = 0; w < 4; ++w) { woff[w] = run; run += wtot[w]; }
        }
        __syncthreads();
        int exc = woff[wv] + inc - v;
        if (b < NBUCK) {
            lstart[b] = exc;
            if (v > 0) gbase[b] = atomicAdd(&bucket_cursor[b], v);
        }
    }
    __syncthreads();
#pragma unroll
    for (int i = 0; i < 16; ++i) {
        if (rows[i] >= 0) {
            int b = rows[i] >> BSHIFT;
            int p = lstart[b] + loff[i];
            lrow[p] = rows[i];
            lcv[p]  = cv[i];
        }
    }
    __syncthreads();
    const int total = lstart[NBUCK - 1] + cnt[NBUCK - 1];
    for (int p = tid; p < total; p += 256) {
        int r = lrow[p];
        int b = r >> BSHIFT;
        int g = gbase[b] + (p - lstart[b]);
        srow[g]    = r;
        scolval[g] = lcv[p];
    }
}

// ---------------- binned scatter pass 2 ----------------
__global__ __launch_bounds__(256) void binpass2_kernel(const int* __restrict__ rowptr,
                                                       const int* __restrict__ srow,
                                                       const int2* __restrict__ scolval,
                                                       int* __restrict__ cursor,
                                                       int2* __restrict__ cedge) {
    const int b = blockIdx.x;
    const int lo = rowptr[b << BSHIFT];
    const int rhiidx = ((b + 1) << BSHIFT);
    const int hi = rowptr[rhiidx > N_NODES ? N_NODES : rhiidx];
    for (int k = lo + threadIdx.x; k < hi; k += 256) {
        int r = srow[k];
        int pos = atomicAdd(&cursor[r], 1);
        cedge[pos] = scolval[k];
    }
}

// ---------------- f32 -> bf16 elementwise ----------------
__global__ __launch_bounds__(256) void cvt_kernel(const float* __restrict__ in,
                                                  ushort* __restrict__ out, int n4) {
    int i = blockIdx.x * 256 + threadIdx.x;
    if (i < n4) {
        float4 v = ((const float4*)in)[i];
        uint2 p;
        p.x = (unsigned)f2b(v.x) | ((unsigned)f2b(v.y) << 16);
        p.y = (unsigned)f2b(v.z) | ((unsigned)f2b(v.w) << 16);
        ((uint2*)out)[i] = p;
    }
}

// ---------------- W [512][256] f32 -> Wt [256][512] bf16 (transpose) ----------------
__global__ __launch_bounds__(256) void wtrans_kernel(const float* __restrict__ W,
                                                     ushort* __restrict__ Wt) {
    int t = blockIdx.x * 256 + threadIdx.x;
    int j = t & 255;
    int k = t >> 8;
    Wt[(size_t)j * 512 + k] = f2b(W[(size_t)k * 256 + j]);
}

// ---------------- CSR SpMM (bf16): TWO nodes per wave, uint4 (16B) gathers ------
// Lanes 0-31 own node A, lanes 32-63 own node B. One gather instruction fetches
// both nodes' 512B rows -> half the VMEM instructions per edge, 2x outstanding
// gathers per wave vs one-node/wave. Iterations = max(degA, degB) (one shfl).
__global__ __launch_bounds__(256) void spmm_kernel(const int* __restrict__ rowptr,
                                                   const int2* __restrict__ cedge,
                                                   const ushort* __restrict__ h,
                                                   ushort* __restrict__ outb) {
    const int tid  = threadIdx.x;
    const int sub  = tid & 31;                  // lane within half-wave
    const int node = blockIdx.x * 8 + ((tid >> 6) << 1) + ((tid >> 5) & 1);
    const uint4* __restrict__ h4 = (const uint4*)h;   // row = 32 uint4
    int k = rowptr[node];
    const int end = rowptr[node + 1];
    int cnt = end - k;
    cnt = max(cnt, __shfl_xor(cnt, 32, 64));    // pair max -> uniform trip count
    float a0 = 0.f, a1 = 0.f, a2 = 0.f, a3 = 0.f,
          a4 = 0.f, a5 = 0.f, a6 = 0.f, a7 = 0.f;
#define EDGE_FMA(e, d)                                              \
    {                                                               \
        float v = __int_as_float((e).y);                            \
        a0 = fmaf(v, __uint_as_float((d).x << 16), a0);             \
        a1 = fmaf(v, __uint_as_float((d).x & 0xffff0000u), a1);     \
        a2 = fmaf(v, __uint_as_float((d).y << 16), a2);             \
        a3 = fmaf(v, __uint_as_float((d).y & 0xffff0000u), a3);     \
        a4 = fmaf(v, __uint_as_float((d).z << 16), a4);             \
        a5 = fmaf(v, __uint_as_float((d).z & 0xffff0000u), a5);     \
        a6 = fmaf(v, __uint_as_float((d).w << 16), a6);             \
        a7 = fmaf(v, __uint_as_float((d).w & 0xffff0000u), a7);     \
    }
    for (int j = 0; j < cnt; j += 4) {
        int2 e0, e1, e2, e3;
        uint4 d0, d1, d2, d3;
        bool p0 = k     < end, p1 = k + 1 < end,
             p2 = k + 2 < end, p3 = k + 3 < end;
        if (p0) { e0 = cedge[k];     d0 = h4[(size_t)e0.x * 32 + sub]; }
        if (p1) { e1 = cedge[k + 1]; d1 = h4[(size_t)e1.x * 32 + sub]; }
        if (p2) { e2 = cedge[k + 2]; d2 = h4[(size_t)e2.x * 32 + sub]; }
        if (p3) { e3 = cedge[k + 3]; d3 = h4[(size_t)e3.x * 32 + sub]; }
        if (p0) EDGE_FMA(e0, d0)
        if (p1) EDGE_FMA(e1, d1)
        if (p2) EDGE_FMA(e2, d2)
        if (p3) EDGE_FMA(e3, d3)
        k += 4;
    }
#undef EDGE_FMA
    uint4 p;
    p.x = (unsigned)f2b(a0) | ((unsigned)f2b(a1) << 16);
    p.y = (unsigned)f2b(a2) | ((unsigned)f2b(a3) << 16);
    p.z = (unsigned)f2b(a4) | ((unsigned)f2b(a5) << 16);
    p.w = (unsigned)f2b(a6) | ((unsigned)f2b(a7) << 16);
    ((uint4*)outb)[(size_t)node * 32 + sub] = p;
}

// ---------------- MFMA concat-GEMM, LDS-staged (m97 2-barrier structure) ----------
template <bool OUT_BF16>
__global__ __launch_bounds__(256, 2) void gemm_mfma_kernel(const ushort* __restrict__ A1,
                                                           const ushort* __restrict__ A2,
                                                           const ushort* __restrict__ Wt,
                                                           const float* __restrict__ bias,
                                                           void* __restrict__ outp) {
    __shared__ __align__(16) char lds[40960];  // As 0..8191, Bs 8192..40959
    const int tid  = threadIdx.x;
    const int wid  = tid >> 6;
    const int lane = tid & 63;
    const int lr   = lane & 15;
    const int g    = lane >> 4;
    const int bm   = blockIdx.x * 64;

    const int l3  = lane >> 3;                 // 0..7 (row within 8-row slot)
    const int cL  = ((lane & 7) ^ l3) * 8;     // logical 8-elem chunk for this slot
    int rowA[2];
#pragma unroll
    for (int p = 0; p < 2; ++p) {
        int r = (p * 4 + wid) * 8 + l3;        // 0..63
        int gr = bm + r;
        rowA[p] = gr < N_NODES ? gr : N_NODES - 1;
    }
    const ushort* wB = Wt + ((size_t)(wid * 8 + l3) << 9) + cL;  // + p*16384 + t*64

    int aoffs[4], boffs[4];
#pragma unroll
    for (int f = 0; f < 4; ++f) {
        aoffs[f] = (((f * 16 + lr) * 128 + g * 16) ^ ((lr & 7) << 4));
        boffs[f] = 8192 + (((wid * 64 + f * 16 + lr) * 128 + g * 16) ^ ((lr & 7) << 4));
    }

    f32x4 acc[4][4];
#pragma unroll
    for (int i = 0; i < 4; ++i)
#pragma unroll
        for (int j = 0; j < 4; ++j) acc[i][j] = (f32x4){0.f, 0.f, 0.f, 0.f};

#pragma unroll 1
    for (int t = 0; t < 8; ++t) {
        const ushort* __restrict__ Ab = (t < 4) ? A1 : A2;
        const int k0 = (t & 3) * 64;
#pragma unroll
        for (int p = 0; p < 2; ++p)
            GLOAD16(Ab + (size_t)rowA[p] * 256 + k0 + cL, lds + (p * 4 + wid) * 1024);
#pragma unroll
        for (int p = 0; p < 8; ++p)
            GLOAD16(wB + p * 16384 + t * 64, lds + 8192 + (p * 4 + wid) * 1024);
        __syncthreads();
#pragma unroll
        for (int kk = 0; kk < 2; ++kk) {
            const int kx = kk << 6;  // advance k-half by XOR (bit 6), not add
            bf16x8 bfr[4];
#pragma unroll
            for (int fc = 0; fc < 4; ++fc)
                bfr[fc] = *(const bf16x8*)(lds + (boffs[fc] ^ kx));
#pragma unroll
            for (int fr = 0; fr < 4; ++fr) {
                bf16x8 af = *(const bf16x8*)(lds + (aoffs[fr] ^ kx));
#pragma unroll
                for (int fc = 0; fc < 4; ++fc)
                    acc[fr][fc] = __builtin_amdgcn_mfma_f32_16x16x32_bf16(af, bfr[fc],
                                                                          acc[fr][fc], 0, 0, 0);
            }
        }
        __syncthreads();
    }

    float bv[4];
#pragma unroll
    for (int fc = 0; fc < 4; ++fc) bv[fc] = bias[wid * 64 + fc * 16 + lr];

    if (!OUT_BF16) {
        float* out = (float*)outp;
#pragma unroll
        for (int fr = 0; fr < 4; ++fr)
#pragma unroll
            for (int reg = 0; reg < 4; ++reg) {
                int row = bm + fr * 16 + g * 4 + reg;
                if (row < N_NODES) {
#pragma unroll
                    for (int fc = 0; fc < 4; ++fc)
                        out[(size_t)row * 256 + wid * 64 + fc * 16 + lr] =
                            acc[fr][fc][reg] + bv[fc];
                }
            }
    } else {
        ushort* out = (ushort*)outp;
        float (*L)[260] = (float(*)[260])lds;
#pragma unroll 1
        for (int half = 0; half < 2; ++half) {
            __syncthreads();
#pragma unroll
            for (int fr2 = 0; fr2 < 2; ++fr2) {
                int fr = half * 2 + fr2;
#pragma unroll
                for (int fc = 0; fc < 4; ++fc)
#pragma unroll
                    for (int reg = 0; reg < 4; ++reg) {
                        int r = fr2 * 16 + g * 4 + reg;
                        L[r][wid * 64 + fc * 16 + lr] = fmaxf(acc[fr][fc][reg] + bv[fc], 0.f);
                    }
            }
            __syncthreads();
            int r  = tid >> 3;
            int ch = tid & 7;
            int grow = bm + half * 32 + r;
            if (grow < N_NODES) {
#pragma unroll
                for (int q = 0; q < 4; ++q) {
                    float4 u0 = *(const float4*)&L[r][ch * 32 + q * 8];
                    float4 u1 = *(const float4*)&L[r][ch * 32 + q * 8 + 4];
                    uint2 pk;
                    pk.x = (unsigned)f2b(u0.x) | ((unsigned)f2b(u0.y) << 16);
                    pk.y = (unsigned)f2b(u0.z) | ((unsigned)f2b(u0.w) << 16);
                    uint2 pk2;
                    pk2.x = (unsigned)f2b(u1.x) | ((unsigned)f2b(u1.y) << 16);
                    pk2.y = (unsigned)f2b(u1.z) | ((unsigned)f2b(u1.w) << 16);
                    uint4 w4 = make_uint4(pk.x, pk.y, pk2.x, pk2.y);
                    *(uint4*)&out[(size_t)grow * 256 + ch * 32 + q * 8] = w4;
                }
            }
        }
    }
}

extern "C" void kernel_launch(void* const* d_in, const int* in_sizes, int n_in,
                              void* d_out, int out_size, void* d_ws, size_t ws_size,
                              hipStream_t stream) {
    const float* x     = (const float*)d_in[0];
    const int*   erow  = (const int*)d_in[1];
    const int*   ecol  = (const int*)d_in[2];
    const float* evalv = (const float*)d_in[3];
    const float* W1    = (const float*)d_in[4];
    const float* b1    = (const float*)d_in[5];
    const float* Wout  = (const float*)d_in[6];
    const float* bout  = (const float*)d_in[7];
    float* out = (float*)d_out;

    char* ws = (char*)d_ws;
    size_t off = 0;
    auto alloc = [&](size_t bytes) -> void* {
        void* p = ws + off;
        off += (bytes + 255) & ~(size_t)255;
        return p;
    };
    ushort* xb       = (ushort*)alloc((size_t)N_NODES * D * 2);     // 51.2 MB
    ushort* h1b      = (ushort*)alloc((size_t)N_NODES * D * 2);     // 51.2 MB
    ushort* neighb   = (ushort*)alloc((size_t)N_NODES * D * 2);     // 51.2 MB
    ushort* W1t      = (ushort*)alloc((size_t)512 * 256 * 2);
    ushort* Woutt    = (ushort*)alloc((size_t)512 * 256 * 2);
    int*    rowptr   = (int*)alloc((size_t)(N_NODES + 1) * sizeof(int));
    int*    deg      = (int*)alloc((size_t)N_NODES * sizeof(int));
    int*    cursor   = (int*)alloc((size_t)N_NODES * sizeof(int));
    int*    blocksum = (int*)alloc((size_t)SCAN_BLOCKS * sizeof(int));
    int*    bcursor  = (int*)alloc((size_t)NBUCK * sizeof(int));
    int*    srow     = (int*)alloc((size_t)N_EDGES * sizeof(int));      // 12.8 MB
    int2*   scolval  = (int2*)alloc((size_t)N_EDGES * sizeof(int2));    // 25.6 MB
    int2*   cedge    = (int2*)alloc((size_t)N_EDGES * sizeof(int2));    // 25.6 MB

    // converts (independent of CSR)
    cvt_kernel<<<(N_NODES * D / 4 + 255) / 256, 256, 0, stream>>>(x, xb, N_NODES * D / 4);
    wtrans_kernel<<<512, 256, 0, stream>>>(W1, W1t);
    wtrans_kernel<<<512, 256, 0, stream>>>(Wout, Woutt);

    // build CSR (reused by both SpMM layers)
    hipMemsetAsync(deg, 0, (size_t)N_NODES * sizeof(int), stream);
    hist_kernel<<<(N_EDGES + 255) / 256, 256, 0, stream>>>(erow, deg);
    scanA_kernel<<<SCAN_BLOCKS, 1024, 0, stream>>>(deg, rowptr, blocksum);
    scanB_kernel<<<1, 64, 0, stream>>>(blocksum, rowptr);
    scanC_kernel<<<SCAN_BLOCKS, 1024, 0, stream>>>(rowptr, blocksum, cursor);
    bucketinit_kernel<<<1, 256, 0, stream>>>(rowptr, bcursor);
    binpass1_kernel<<<(N_EDGES + EPB - 1) / EPB, 256, 0, stream>>>(erow, ecol, evalv,
                                                                   bcursor, srow, scolval);
    binpass2_kernel<<<NBUCK, 256, 0, stream>>>(rowptr, srow, scolval, cursor, cedge);

    const int gblocks = (N_NODES + 63) / 64;  // 1563
    // layer 1
    spmm_kernel<<<N_NODES / 8, 256, 0, stream>>>(rowptr, cedge, xb, neighb);
    gemm_mfma_kernel<true><<<gblocks, 256, 0, stream>>>(xb, neighb, W1t, b1, h1b);
    // layer 2
    spmm_kernel<<<N_NODES / 8, 256, 0, stream>>>(rowptr, cedge, h1b, neighb);
    gemm_mfma_kernel<false><<<gblocks, 256, 0, stream>>>(h1b, neighb, Woutt, bout, out);
}

// Round 9
// 820.342 us; speedup vs baseline: 1.3324x; 1.2113x over previous
//
#include <hip/hip_runtime.h>
#include <cstddef>
#include <cstdint>

#define N_NODES 100000
#define N_EDGES 3200000
#define D 256
#define SCAN_BLOCKS ((N_NODES + 1023) / 1024)  // 98
#define BSHIFT 9                                // 512 rows per bucket
#define NBUCK ((N_NODES + (1 << BSHIFT) - 1) >> BSHIFT)  // 196
#define EPB 4096                                // edges per pass-1 block

typedef __attribute__((ext_vector_type(8))) short bf16x8;
typedef __attribute__((ext_vector_type(4))) float f32x4;
typedef unsigned int u32;
typedef unsigned long long u64;

#define GLOAD16(gsrc, ldst)                                                      \
    __builtin_amdgcn_global_load_lds(                                            \
        (const __attribute__((address_space(1))) void*)(gsrc),                   \
        (__attribute__((address_space(3))) void*)(ldst), 16, 0, 0)

__device__ __forceinline__ ushort f2b(float f) {  // f32 -> bf16 RNE
    unsigned u = __float_as_uint(f);
    return (ushort)((u + 0x7fffu + ((u >> 16) & 1u)) >> 16);
}

// ---------------- degree histogram ----------------
__global__ __launch_bounds__(256) void hist_kernel(const int* __restrict__ row,
                                                   int* __restrict__ deg) {
    int e = blockIdx.x * 256 + threadIdx.x;
    if (e < N_EDGES) atomicAdd(&deg[row[e]], 1);
}

// ---------------- scan stage A ----------------
__global__ __launch_bounds__(1024) void scanA_kernel(const int* __restrict__ deg,
                                                     int* __restrict__ rowptr,
                                                     int* __restrict__ blocksum) {
    __shared__ int waveTot[16];
    __shared__ int waveOff[16];
    const int tid  = threadIdx.x;
    const int lane = tid & 63;
    const int wv   = tid >> 6;
    const int idx  = blockIdx.x * 1024 + tid;
    int v = (idx < N_NODES) ? deg[idx] : 0;
    int inc = v;
#pragma unroll
    for (int off = 1; off < 64; off <<= 1) {
        int up = __shfl_up(inc, off, 64);
        if (lane >= off) inc += up;
    }
    if (lane == 63) waveTot[wv] = inc;
    __syncthreads();
    if (tid == 0) {
        int run = 0;
#pragma unroll
        for (int w = 0; w < 16; ++w) { waveOff[w] = run; run += waveTot[w]; }
        blocksum[blockIdx.x] = run;
    }
    __syncthreads();
    if (idx < N_NODES) rowptr[idx] = waveOff[wv] + (inc - v);
}

// ---------------- scan stage B ----------------
__global__ void scanB_kernel(int* __restrict__ blocksum, int* __restrict__ rowptr) {
    if (threadIdx.x == 0 && blockIdx.x == 0) {
        int run = 0;
        for (int b = 0; b < SCAN_BLOCKS; ++b) {
            int t = blocksum[b];
            blocksum[b] = run;
            run += t;
        }
        rowptr[N_NODES] = run;
    }
}

// ---------------- scan stage C ----------------
__global__ __launch_bounds__(1024) void scanC_kernel(int* __restrict__ rowptr,
                                                     const int* __restrict__ blocksum) {
    const int idx = blockIdx.x * 1024 + threadIdx.x;
    if (idx < N_NODES) rowptr[idx] += blocksum[blockIdx.x];
}

// ---------------- bucket cursor init ----------------
__global__ void bucketinit_kernel(const int* __restrict__ rowptr,
                                  int* __restrict__ bucket_cursor) {
    int b = blockIdx.x * 256 + threadIdx.x;
    if (b < NBUCK) bucket_cursor[b] = rowptr[b << BSHIFT];
}

// ---------------- binned scatter pass 1 ----------------
__global__ __launch_bounds__(256) void binpass1_kernel(const int* __restrict__ erow,
                                                       const int* __restrict__ ecol,
                                                       const float* __restrict__ evalv,
                                                       int* __restrict__ bucket_cursor,
                                                       int* __restrict__ srow,
                                                       int2* __restrict__ scolval) {
    __shared__ int cnt[NBUCK];
    __shared__ int lstart[NBUCK];
    __shared__ int gbase[NBUCK];
    __shared__ int wtot[4];
    __shared__ int woff[4];
    __shared__ int   lrow[EPB];   // 16 KB
    __shared__ int2  lcv[EPB];    // 32 KB
    const int tid = threadIdx.x;
    const size_t base = (size_t)blockIdx.x * EPB;
    for (int b = tid; b < NBUCK; b += 256) cnt[b] = 0;
    __syncthreads();
    int rows[16];
    int2 cv[16];
    int loff[16];
#pragma unroll
    for (int i = 0; i < 16; ++i) {
        size_t e = base + (size_t)i * 256 + tid;
        if (e < N_EDGES) {
            int r = erow[e];
            rows[i] = r;
            cv[i] = make_int2(ecol[e], __float_as_int(evalv[e]));
            loff[i] = atomicAdd(&cnt[r >> BSHIFT], 1);
        } else {
            rows[i] = -1;
        }
    }
    __syncthreads();
    {
        int b = tid;
        int v = (b < NBUCK) ? cnt[b] : 0;
        int lane = tid & 63, wv = tid >> 6;
        int inc = v;
#pragma unroll
        for (int off = 1; off < 64; off <<= 1) {
            int u = __shfl_up(inc, off, 64);
            if (lane >= off) inc += u;
        }
        if (lane == 63) wtot[wv] = inc;
        __syncthreads();
        if (tid == 0) {
            int run = 0;
#pragma unroll
            for (int w = 0; w < 4; ++w) { woff[w] = run; run += wtot[w]; }
        }
        __syncthreads();
        int exc = woff[wv] + inc - v;
        if (b < NBUCK) {
            lstart[b] = exc;
            if (v > 0) gbase[b] = atomicAdd(&bucket_cursor[b], v);
        }
    }
    __syncthreads();
#pragma unroll
    for (int i = 0; i < 16; ++i) {
        if (rows[i] >= 0) {
            int b = rows[i] >> BSHIFT;
            int p = lstart[b] + loff[i];
            lrow[p] = rows[i];
            lcv[p]  = cv[i];
        }
    }
    __syncthreads();
    const int total = lstart[NBUCK - 1] + cnt[NBUCK - 1];
    for (int p = tid; p < total; p += 256) {
        int r = lrow[p];
        int b = r >> BSHIFT;
        int g = gbase[b] + (p - lstart[b]);
        srow[g]    = r;
        scolval[g] = lcv[p];
    }
}

// ---------------- binned scatter pass 2 (LDS row cursors) ----------------
__global__ __launch_bounds__(256) void binpass2_kernel(const int* __restrict__ rowptr,
                                                       const int* __restrict__ srow,
                                                       const int2* __restrict__ scolval,
                                                       int2* __restrict__ cedge) {
    __shared__ int lcur[1 << BSHIFT];
    const int b  = blockIdx.x;
    const int r0 = b << BSHIFT;
    const int rend = (r0 + (1 << BSHIFT) > N_NODES) ? N_NODES : r0 + (1 << BSHIFT);
    const int nrows = rend - r0;
    for (int i = threadIdx.x; i < nrows; i += 256) lcur[i] = rowptr[r0 + i];
    __syncthreads();
    const int lo = rowptr[r0];
    const int hi = rowptr[rend];
    for (int k = lo + threadIdx.x; k < hi; k += 256) {
        int r = srow[k];
        int2 cv = scolval[k];
        int pos = atomicAdd(&lcur[r - r0], 1);
        cedge[pos] = cv;
    }
}

// ---------------- f32 -> bf16 elementwise ----------------
__global__ __launch_bounds__(256) void cvt_kernel(const float* __restrict__ in,
                                                  ushort* __restrict__ out, int n4) {
    int i = blockIdx.x * 256 + threadIdx.x;
    if (i < n4) {
        float4 v = ((const float4*)in)[i];
        uint2 p;
        p.x = (unsigned)f2b(v.x) | ((unsigned)f2b(v.y) << 16);
        p.y = (unsigned)f2b(v.z) | ((unsigned)f2b(v.w) << 16);
        ((uint2*)out)[i] = p;
    }
}

// ---------------- W [512][256] f32 -> Wt [256][512] bf16 (transpose) ----------------
__global__ __launch_bounds__(256) void wtrans_kernel(const float* __restrict__ W,
                                                     ushort* __restrict__ Wt) {
    int t = blockIdx.x * 256 + threadIdx.x;
    int j = t & 255;
    int k = t >> 8;
    Wt[(size_t)j * 512 + k] = f2b(W[(size_t)k * 256 + j]);
}

// ---------------- CSR SpMM (bf16 features): one wave per node (R6-proven) ---------
__global__ __launch_bounds__(256) void spmm_kernel(const int* __restrict__ rowptr,
                                                   const int2* __restrict__ cedge,
                                                   const ushort* __restrict__ h,
                                                   ushort* __restrict__ outb) {
    const int node = (blockIdx.x << 2) + (threadIdx.x >> 6);
    const int lane = threadIdx.x & 63;
    const uint2* __restrict__ h2 = (const uint2*)h;
    int k = rowptr[node];
    const int end = rowptr[node + 1];
    float a0 = 0.f, a1 = 0.f, a2 = 0.f, a3 = 0.f;
#define EDGE_FMA(e, d)                                              \
    {                                                               \
        float v = __int_as_float((e).y);                            \
        a0 = fmaf(v, __uint_as_float((d).x << 16), a0);             \
        a1 = fmaf(v, __uint_as_float((d).x & 0xffff0000u), a1);     \
        a2 = fmaf(v, __uint_as_float((d).y << 16), a2);             \
        a3 = fmaf(v, __uint_as_float((d).y & 0xffff0000u), a3);     \
    }
    for (; k + 4 <= end; k += 4) {
        int2 e0 = cedge[k];
        int2 e1 = cedge[k + 1];
        int2 e2 = cedge[k + 2];
        int2 e3 = cedge[k + 3];
        uint2 d0 = h2[(size_t)e0.x * 64 + lane];
        uint2 d1 = h2[(size_t)e1.x * 64 + lane];
        uint2 d2 = h2[(size_t)e2.x * 64 + lane];
        uint2 d3 = h2[(size_t)e3.x * 64 + lane];
        EDGE_FMA(e0, d0)
        EDGE_FMA(e1, d1)
        EDGE_FMA(e2, d2)
        EDGE_FMA(e3, d3)
    }
    for (; k < end; ++k) {
        int2 e = cedge[k];
        uint2 d = h2[(size_t)e.x * 64 + lane];
        EDGE_FMA(e, d)
    }
#undef EDGE_FMA
    uint2 p;
    p.x = (unsigned)f2b(a0) | ((unsigned)f2b(a1) << 16);
    p.y = (unsigned)f2b(a2) | ((unsigned)f2b(a3) << 16);
    ((uint2*)outb)[(size_t)node * 64 + lane] = p;
}

// ---------------- MFMA concat-GEMM: double-buffered LDS + counted vmcnt -----------
// Per iter: STAGE(next buf) -> s_waitcnt vmcnt(10) (next's 10 loads stay in
// flight) -> raw s_barrier -> MFMA(cur) -> raw s_barrier. No __syncthreads in
// the K-loop = no full vmcnt(0) drain (the m97 stall). Race-checked: stage at
// iter t targets buf(t+1)=buf(t^1); all frag ds_reads are consumed by MFMAs
// (lgkmcnt waits) before barrier2, so overwrite of buf(t) at iter t+1 is safe.
#define STAGE_TILE(bufbase, tt)                                                  \
    {                                                                            \
        const ushort* Ab_ = ((tt) < 4) ? A1 : A2;                                \
        const int k0_ = ((tt) & 3) * 64;                                         \
        _Pragma("unroll")                                                        \
        for (int p = 0; p < 2; ++p)                                              \
            GLOAD16(Ab_ + (size_t)rowA[p] * 256 + k0_ + cL,                      \
                    lds + (bufbase) + (p * 4 + wid) * 1024);                     \
        _Pragma("unroll")                                                        \
        for (int p = 0; p < 8; ++p)                                              \
            GLOAD16(wB + p * 16384 + (tt) * 64,                                  \
                    lds + (bufbase) + 8192 + (p * 4 + wid) * 1024);              \
    }

template <bool OUT_BF16>
__global__ __launch_bounds__(256, 2) void gemm_mfma_kernel(const ushort* __restrict__ A1,
                                                           const ushort* __restrict__ A2,
                                                           const ushort* __restrict__ Wt,
                                                           const float* __restrict__ bias,
                                                           void* __restrict__ outp) {
    __shared__ __align__(16) char lds[81920];  // 2 x (A 8KB + B 32KB)
    const int tid  = threadIdx.x;
    const int wid  = tid >> 6;
    const int lane = tid & 63;
    const int lr   = lane & 15;
    const int g    = lane >> 4;
    const int bm   = blockIdx.x * 64;

    const int l3  = lane >> 3;                 // 0..7 (row within 8-row slot)
    const int cL  = ((lane & 7) ^ l3) * 8;     // inverse-swizzled source chunk
    int rowA[2];
#pragma unroll
    for (int p = 0; p < 2; ++p) {
        int r = (p * 4 + wid) * 8 + l3;        // 0..63
        int gr = bm + r;
        rowA[p] = gr < N_NODES ? gr : N_NODES - 1;
    }
    const ushort* wB = Wt + ((size_t)(wid * 8 + l3) << 9) + cL;  // + p*16384 + t*64

    int aoffs[4], boffs[4];
#pragma unroll
    for (int f = 0; f < 4; ++f) {
        aoffs[f] = (((f * 16 + lr) * 128 + g * 16) ^ ((lr & 7) << 4));
        boffs[f] = 8192 + (((wid * 64 + f * 16 + lr) * 128 + g * 16) ^ ((lr & 7) << 4));
    }

    f32x4 acc[4][4];
#pragma unroll
    for (int i = 0; i < 4; ++i)
#pragma unroll
        for (int j = 0; j < 4; ++j) acc[i][j] = (f32x4){0.f, 0.f, 0.f, 0.f};

    STAGE_TILE(0, 0);  // prologue: tile 0 into buf 0

#pragma unroll 1
    for (int t = 0; t < 8; ++t) {
        const int cb = (t & 1) * 40960;
        if (t < 7) {
            STAGE_TILE(40960 - cb, t + 1);                      // next tile -> other buf
            asm volatile("s_waitcnt vmcnt(10)" ::: "memory");   // cur's loads done
        } else {
            asm volatile("s_waitcnt vmcnt(0)" ::: "memory");
        }
        __builtin_amdgcn_sched_barrier(0);
        __builtin_amdgcn_s_barrier();                           // all waves: cur ready
        __builtin_amdgcn_sched_barrier(0);
#pragma unroll
        for (int kk = 0; kk < 2; ++kk) {
            const int kx = kk << 6;  // k-half advances via XOR (bit 6), not add
            bf16x8 bfr[4];
#pragma unroll
            for (int fc = 0; fc < 4; ++fc)
                bfr[fc] = *(const bf16x8*)(lds + cb + (boffs[fc] ^ kx));
#pragma unroll
            for (int fr = 0; fr < 4; ++fr) {
                bf16x8 af = *(const bf16x8*)(lds + cb + (aoffs[fr] ^ kx));
#pragma unroll
                for (int fc = 0; fc < 4; ++fc)
                    acc[fr][fc] = __builtin_amdgcn_mfma_f32_16x16x32_bf16(af, bfr[fc],
                                                                          acc[fr][fc], 0, 0, 0);
            }
        }
        __builtin_amdgcn_s_barrier();                           // all waves done with cur
    }

    float bv[4];
#pragma unroll
    for (int fc = 0; fc < 4; ++fc) bv[fc] = bias[wid * 64 + fc * 16 + lr];

    if (!OUT_BF16) {
        float* out = (float*)outp;
#pragma unroll
        for (int fr = 0; fr < 4; ++fr)
#pragma unroll
            for (int reg = 0; reg < 4; ++reg) {
                int row = bm + fr * 16 + g * 4 + reg;
                if (row < N_NODES) {
#pragma unroll
                    for (int fc = 0; fc < 4; ++fc)
                        out[(size_t)row * 256 + wid * 64 + fc * 16 + lr] =
                            acc[fr][fc][reg] + bv[fc];
                }
            }
    } else {
        ushort* out = (ushort*)outp;
        float (*L)[260] = (float(*)[260])lds;
#pragma unroll 1
        for (int half = 0; half < 2; ++half) {
            __syncthreads();
#pragma unroll
            for (int fr2 = 0; fr2 < 2; ++fr2) {
                int fr = half * 2 + fr2;
#pragma unroll
                for (int fc = 0; fc < 4; ++fc)
#pragma unroll
                    for (int reg = 0; reg < 4; ++reg) {
                        int r = fr2 * 16 + g * 4 + reg;
                        L[r][wid * 64 + fc * 16 + lr] = fmaxf(acc[fr][fc][reg] + bv[fc], 0.f);
                    }
            }
            __syncthreads();
            int r  = tid >> 3;
            int ch = tid & 7;
            int grow = bm + half * 32 + r;
            if (grow < N_NODES) {
#pragma unroll
                for (int q = 0; q < 4; ++q) {
                    float4 u0 = *(const float4*)&L[r][ch * 32 + q * 8];
                    float4 u1 = *(const float4*)&L[r][ch * 32 + q * 8 + 4];
                    uint2 pk;
                    pk.x = (unsigned)f2b(u0.x) | ((unsigned)f2b(u0.y) << 16);
                    pk.y = (unsigned)f2b(u0.z) | ((unsigned)f2b(u0.w) << 16);
                    uint2 pk2;
                    pk2.x = (unsigned)f2b(u1.x) | ((unsigned)f2b(u1.y) << 16);
                    pk2.y = (unsigned)f2b(u1.z) | ((unsigned)f2b(u1.w) << 16);
                    uint4 w4 = make_uint4(pk.x, pk.y, pk2.x, pk2.y);
                    *(uint4*)&out[(size_t)grow * 256 + ch * 32 + q * 8] = w4;
                }
            }
        }
    }
}

extern "C" void kernel_launch(void* const* d_in, const int* in_sizes, int n_in,
                              void* d_out, int out_size, void* d_ws, size_t ws_size,
                              hipStream_t stream) {
    const float* x     = (const float*)d_in[0];
    const int*   erow  = (const int*)d_in[1];
    const int*   ecol  = (const int*)d_in[2];
    const float* evalv = (const float*)d_in[3];
    const float* W1    = (const float*)d_in[4];
    const float* b1    = (const float*)d_in[5];
    const float* Wout  = (const float*)d_in[6];
    const float* bout  = (const float*)d_in[7];
    float* out = (float*)d_out;

    char* ws = (char*)d_ws;
    size_t off = 0;
    auto alloc = [&](size_t bytes) -> void* {
        void* p = ws + off;
        off += (bytes + 255) & ~(size_t)255;
        return p;
    };
    ushort* xb       = (ushort*)alloc((size_t)N_NODES * D * 2);     // 51.2 MB
    ushort* h1b      = (ushort*)alloc((size_t)N_NODES * D * 2);     // 51.2 MB
    ushort* neighb   = (ushort*)alloc((size_t)N_NODES * D * 2);     // 51.2 MB
    ushort* W1t      = (ushort*)alloc((size_t)512 * 256 * 2);
    ushort* Woutt    = (ushort*)alloc((size_t)512 * 256 * 2);
    int*    rowptr   = (int*)alloc((size_t)(N_NODES + 1) * sizeof(int));
    int*    deg      = (int*)alloc((size_t)N_NODES * sizeof(int));
    int*    blocksum = (int*)alloc((size_t)SCAN_BLOCKS * sizeof(int));
    int*    bcursor  = (int*)alloc((size_t)NBUCK * sizeof(int));
    int*    srow     = (int*)alloc((size_t)N_EDGES * sizeof(int));      // 12.8 MB
    int2*   scolval  = (int2*)alloc((size_t)N_EDGES * sizeof(int2));    // 25.6 MB
    int2*   cedge    = (int2*)alloc((size_t)N_EDGES * sizeof(int2));    // 25.6 MB

    // converts (independent of CSR)
    cvt_kernel<<<(N_NODES * D / 4 + 255) / 256, 256, 0, stream>>>(x, xb, N_NODES * D / 4);
    wtrans_kernel<<<512, 256, 0, stream>>>(W1, W1t);
    wtrans_kernel<<<512, 256, 0, stream>>>(Wout, Woutt);

    // build CSR (reused by both SpMM layers)
    hipMemsetAsync(deg, 0, (size_t)N_NODES * sizeof(int), stream);
    hist_kernel<<<(N_EDGES + 255) / 256, 256, 0, stream>>>(erow, deg);
    scanA_kernel<<<SCAN_BLOCKS, 1024, 0, stream>>>(deg, rowptr, blocksum);
    scanB_kernel<<<1, 64, 0, stream>>>(blocksum, rowptr);
    scanC_kernel<<<SCAN_BLOCKS, 1024, 0, stream>>>(rowptr, blocksum);
    bucketinit_kernel<<<1, 256, 0, stream>>>(rowptr, bcursor);
    binpass1_kernel<<<(N_EDGES + EPB - 1) / EPB, 256, 0, stream>>>(erow, ecol, evalv,
                                                                   bcursor, srow, scolval);
    binpass2_kernel<<<NBUCK, 256, 0, stream>>>(rowptr, srow, scolval, cedge);

    const int gblocks = (N_NODES + 63) / 64;  // 1563
    // layer 1
    spmm_kernel<<<N_NODES / 4, 256, 0, stream>>>(rowptr, cedge, xb, neighb);
    gemm_mfma_kernel<true><<<gblocks, 256, 0, stream>>>(xb, neighb, W1t, b1, h1b);
    // layer 2
    spmm_kernel<<<N_NODES / 4, 256, 0, stream>>>(rowptr, cedge, h1b, neighb);
    gemm_mfma_kernel<false><<<gblocks, 256, 0, stream>>>(h1b, neighb, Woutt, bout, out);
}

// Round 10
// 794.292 us; speedup vs baseline: 1.3761x; 1.0328x over previous
//
#include <hip/hip_runtime.h>
#include <cstddef>
#include <cstdint>

#define N_NODES 100000
#define N_EDGES 3200000
#define D 256
#define SCAN_BLOCKS ((N_NODES + 1023) / 1024)  // 98
#define BSHIFT 9                                // 512 rows per bucket
#define NBUCK ((N_NODES + (1 << BSHIFT) - 1) >> BSHIFT)  // 196
#define EPB 4096                                // edges per pass-1 block
#define CAP 20480                               // staging slots per bucket (mean 16384 + 32 sigma)

typedef __attribute__((ext_vector_type(8))) short bf16x8;
typedef __attribute__((ext_vector_type(4))) float f32x4;
typedef unsigned int u32;
typedef unsigned long long u64;

#define GLOAD16(gsrc, ldst)                                                      \
    __builtin_amdgcn_global_load_lds(                                            \
        (const __attribute__((address_space(1))) void*)(gsrc),                   \
        (__attribute__((address_space(3))) void*)(ldst), 16, 0, 0)

__device__ __forceinline__ ushort f2b(float f) {  // f32 -> bf16 RNE
    unsigned u = __float_as_uint(f);
    return (ushort)((u + 0x7fffu + ((u >> 16) & 1u)) >> 16);
}

// ---------------- scan stage A ----------------
__global__ __launch_bounds__(1024) void scanA_kernel(const int* __restrict__ deg,
                                                     int* __restrict__ rowptr,
                                                     int* __restrict__ blocksum) {
    __shared__ int waveTot[16];
    __shared__ int waveOff[16];
    const int tid  = threadIdx.x;
    const int lane = tid & 63;
    const int wv   = tid >> 6;
    const int idx  = blockIdx.x * 1024 + tid;
    int v = (idx < N_NODES) ? deg[idx] : 0;
    int inc = v;
#pragma unroll
    for (int off = 1; off < 64; off <<= 1) {
        int up = __shfl_up(inc, off, 64);
        if (lane >= off) inc += up;
    }
    if (lane == 63) waveTot[wv] = inc;
    __syncthreads();
    if (tid == 0) {
        int run = 0;
#pragma unroll
        for (int w = 0; w < 16; ++w) { waveOff[w] = run; run += waveTot[w]; }
        blocksum[blockIdx.x] = run;
    }
    __syncthreads();
    if (idx < N_NODES) rowptr[idx] = waveOff[wv] + (inc - v);
}

// ---------------- scan stage B ----------------
__global__ void scanB_kernel(int* __restrict__ blocksum, int* __restrict__ rowptr) {
    if (threadIdx.x == 0 && blockIdx.x == 0) {
        int run = 0;
        for (int b = 0; b < SCAN_BLOCKS; ++b) {
            int t = blocksum[b];
            blocksum[b] = run;
            run += t;
        }
        rowptr[N_NODES] = run;
    }
}

// ---------------- scan stage C ----------------
__global__ __launch_bounds__(1024) void scanC_kernel(int* __restrict__ rowptr,
                                                     const int* __restrict__ blocksum) {
    const int idx = blockIdx.x * 1024 + threadIdx.x;
    if (idx < N_NODES) rowptr[idx] += blocksum[blockIdx.x];
}

// ---------------- bucket cursor init (fixed-capacity slots) ----------------
__global__ void cursorinit_kernel(int* __restrict__ bucket_cursor) {
    int b = blockIdx.x * 256 + threadIdx.x;
    if (b < NBUCK) bucket_cursor[b] = b * CAP;
}

// ---------------- binned scatter pass 1 (fused degree histogram) ----------------
// Packs (r & 511) into bits 17-25 of the col word; staging slot base = b*CAP
// (independent of rowptr, so this runs BEFORE the scan; hist is fused here).
__global__ __launch_bounds__(256) void binpass1_kernel(const int* __restrict__ erow,
                                                       const int* __restrict__ ecol,
                                                       const float* __restrict__ evalv,
                                                       int* __restrict__ deg,
                                                       int* __restrict__ bucket_cursor,
                                                       int2* __restrict__ staging) {
    __shared__ int cnt[NBUCK];
    __shared__ int lstart[NBUCK];
    __shared__ int gbase[NBUCK];
    __shared__ int wtot[4];
    __shared__ int woff[4];
    __shared__ int2 lcv[EPB];            // 32 KB (packed col+row | val)
    __shared__ unsigned char lbb[EPB];   // 4 KB bucket id per staged slot
    const int tid = threadIdx.x;
    const size_t base = (size_t)blockIdx.x * EPB;
    for (int b = tid; b < NBUCK; b += 256) cnt[b] = 0;
    __syncthreads();
    int bb[16];
    int2 pcv[16];
    int loff[16];
#pragma unroll
    for (int i = 0; i < 16; ++i) {
        size_t e = base + (size_t)i * 256 + tid;
        if (e < N_EDGES) {
            int r = erow[e];
            atomicAdd(&deg[r], 1);            // fused histogram
            int b = r >> BSHIFT;
            bb[i] = b;
            pcv[i] = make_int2(ecol[e] | ((r & ((1 << BSHIFT) - 1)) << 17),
                               __float_as_int(evalv[e]));
            loff[i] = atomicAdd(&cnt[b], 1);
        } else {
            bb[i] = -1;
        }
    }
    __syncthreads();
    {   // exclusive scan of cnt[0..NBUCK) + claim global staging ranges
        int b = tid;
        int v = (b < NBUCK) ? cnt[b] : 0;
        int lane = tid & 63, wv = tid >> 6;
        int inc = v;
#pragma unroll
        for (int off = 1; off < 64; off <<= 1) {
            int u = __shfl_up(inc, off, 64);
            if (lane >= off) inc += u;
        }
        if (lane == 63) wtot[wv] = inc;
        __syncthreads();
        if (tid == 0) {
            int run = 0;
#pragma unroll
            for (int w = 0; w < 4; ++w) { woff[w] = run; run += wtot[w]; }
        }
        __syncthreads();
        int exc = woff[wv] + inc - v;
        if (b < NBUCK) {
            lstart[b] = exc;
            if (v > 0) gbase[b] = atomicAdd(&bucket_cursor[b], v);
        }
    }
    __syncthreads();
#pragma unroll
    for (int i = 0; i < 16; ++i) {
        if (bb[i] >= 0) {
            int p = lstart[bb[i]] + loff[i];
            lcv[p] = pcv[i];
            lbb[p] = (unsigned char)bb[i];
        }
    }
    __syncthreads();
    const int total = lstart[NBUCK - 1] + cnt[NBUCK - 1];
    for (int p = tid; p < total; p += 256) {
        int b = lbb[p];
        int g = gbase[b] + (p - lstart[b]);
        staging[g] = lcv[p];
    }
}

// ---------------- binned scatter pass 2 (LDS row cursors, packed staging) --------
__global__ __launch_bounds__(256) void binpass2_kernel(const int* __restrict__ rowptr,
                                                       const int* __restrict__ bucket_cursor,
                                                       const int2* __restrict__ staging,
                                                       int2* __restrict__ cedge) {
    __shared__ int lcur[1 << BSHIFT];
    const int b  = blockIdx.x;
    const int r0 = b << BSHIFT;
    const int rend = (r0 + (1 << BSHIFT) > N_NODES) ? N_NODES : r0 + (1 << BSHIFT);
    const int nrows = rend - r0;
    for (int i = threadIdx.x; i < nrows; i += 256) lcur[i] = rowptr[r0 + i];
    __syncthreads();
    const int lo = b * CAP;
    const int hi = bucket_cursor[b];
    for (int k = lo + threadIdx.x; k < hi; k += 256) {
        int2 e = staging[k];
        int rloc = ((u32)e.x) >> 17;
        int col  = e.x & 0x1FFFF;
        int pos = atomicAdd(&lcur[rloc], 1);
        cedge[pos] = make_int2(col, e.y);
    }
}

// ---------------- f32 -> bf16 elementwise ----------------
__global__ __launch_bounds__(256) void cvt_kernel(const float* __restrict__ in,
                                                  ushort* __restrict__ out, int n4) {
    int i = blockIdx.x * 256 + threadIdx.x;
    if (i < n4) {
        float4 v = ((const float4*)in)[i];
        uint2 p;
        p.x = (unsigned)f2b(v.x) | ((unsigned)f2b(v.y) << 16);
        p.y = (unsigned)f2b(v.z) | ((unsigned)f2b(v.w) << 16);
        ((uint2*)out)[i] = p;
    }
}

// ---------------- W [512][256] f32 -> Wt [256][512] bf16 (transpose) ----------------
__global__ __launch_bounds__(256) void wtrans_kernel(const float* __restrict__ W,
                                                     ushort* __restrict__ Wt) {
    int t = blockIdx.x * 256 + threadIdx.x;
    int j = t & 255;
    int k = t >> 8;
    Wt[(size_t)j * 512 + k] = f2b(W[(size_t)k * 256 + j]);
}

// ---------------- CSR SpMM (bf16 features): one wave per node (R6-proven) ---------
__global__ __launch_bounds__(256) void spmm_kernel(const int* __restrict__ rowptr,
                                                   const int2* __restrict__ cedge,
                                                   const ushort* __restrict__ h,
                                                   ushort* __restrict__ outb) {
    const int node = (blockIdx.x << 2) + (threadIdx.x >> 6);
    const int lane = threadIdx.x & 63;
    const uint2* __restrict__ h2 = (const uint2*)h;
    int k = rowptr[node];
    const int end = rowptr[node + 1];
    float a0 = 0.f, a1 = 0.f, a2 = 0.f, a3 = 0.f;
#define EDGE_FMA(e, d)                                              \
    {                                                               \
        float v = __int_as_float((e).y);                            \
        a0 = fmaf(v, __uint_as_float((d).x << 16), a0);             \
        a1 = fmaf(v, __uint_as_float((d).x & 0xffff0000u), a1);     \
        a2 = fmaf(v, __uint_as_float((d).y << 16), a2);             \
        a3 = fmaf(v, __uint_as_float((d).y & 0xffff0000u), a3);     \
    }
    for (; k + 4 <= end; k += 4) {
        int2 e0 = cedge[k];
        int2 e1 = cedge[k + 1];
        int2 e2 = cedge[k + 2];
        int2 e3 = cedge[k + 3];
        uint2 d0 = h2[(size_t)e0.x * 64 + lane];
        uint2 d1 = h2[(size_t)e1.x * 64 + lane];
        uint2 d2 = h2[(size_t)e2.x * 64 + lane];
        uint2 d3 = h2[(size_t)e3.x * 64 + lane];
        EDGE_FMA(e0, d0)
        EDGE_FMA(e1, d1)
        EDGE_FMA(e2, d2)
        EDGE_FMA(e3, d3)
    }
    for (; k < end; ++k) {
        int2 e = cedge[k];
        uint2 d = h2[(size_t)e.x * 64 + lane];
        EDGE_FMA(e, d)
    }
#undef EDGE_FMA
    uint2 p;
    p.x = (unsigned)f2b(a0) | ((unsigned)f2b(a1) << 16);
    p.y = (unsigned)f2b(a2) | ((unsigned)f2b(a3) << 16);
    ((uint2*)outb)[(size_t)node * 64 + lane] = p;
}

// ---------------- MFMA concat-GEMM: double-buffered LDS + counted vmcnt -----------
#define STAGE_TILE(bufbase, tt)                                                  \
    {                                                                            \
        const ushort* Ab_ = ((tt) < 4) ? A1 : A2;                                \
        const int k0_ = ((tt) & 3) * 64;                                         \
        _Pragma("unroll")                                                        \
        for (int p = 0; p < 2; ++p)                                              \
            GLOAD16(Ab_ + (size_t)rowA[p] * 256 + k0_ + cL,                      \
                    lds + (bufbase) + (p * 4 + wid) * 1024);                     \
        _Pragma("unroll")                                                        \
        for (int p = 0; p < 8; ++p)                                              \
            GLOAD16(wB + p * 16384 + (tt) * 64,                                  \
                    lds + (bufbase) + 8192 + (p * 4 + wid) * 1024);              \
    }

template <bool OUT_BF16>
__global__ __launch_bounds__(256, 2) void gemm_mfma_kernel(const ushort* __restrict__ A1,
                                                           const ushort* __restrict__ A2,
                                                           const ushort* __restrict__ Wt,
                                                           const float* __restrict__ bias,
                                                           void* __restrict__ outp) {
    __shared__ __align__(16) char lds[81920];  // 2 x (A 8KB + B 32KB)
    const int tid  = threadIdx.x;
    const int wid  = tid >> 6;
    const int lane = tid & 63;
    const int lr   = lane & 15;
    const int g    = lane >> 4;
    const int bm   = blockIdx.x * 64;

    const int l3  = lane >> 3;                 // 0..7 (row within 8-row slot)
    const int cL  = ((lane & 7) ^ l3) * 8;     // inverse-swizzled source chunk
    int rowA[2];
#pragma unroll
    for (int p = 0; p < 2; ++p) {
        int r = (p * 4 + wid) * 8 + l3;        // 0..63
        int gr = bm + r;
        rowA[p] = gr < N_NODES ? gr : N_NODES - 1;
    }
    const ushort* wB = Wt + ((size_t)(wid * 8 + l3) << 9) + cL;  // + p*16384 + t*64

    int aoffs[4], boffs[4];
#pragma unroll
    for (int f = 0; f < 4; ++f) {
        aoffs[f] = (((f * 16 + lr) * 128 + g * 16) ^ ((lr & 7) << 4));
        boffs[f] = 8192 + (((wid * 64 + f * 16 + lr) * 128 + g * 16) ^ ((lr & 7) << 4));
    }

    f32x4 acc[4][4];
#pragma unroll
    for (int i = 0; i < 4; ++i)
#pragma unroll
        for (int j = 0; j < 4; ++j) acc[i][j] = (f32x4){0.f, 0.f, 0.f, 0.f};

    STAGE_TILE(0, 0);  // prologue: tile 0 into buf 0

#pragma unroll 1
    for (int t = 0; t < 8; ++t) {
        const int cb = (t & 1) * 40960;
        if (t < 7) {
            STAGE_TILE(40960 - cb, t + 1);                      // next tile -> other buf
            asm volatile("s_waitcnt vmcnt(10)" ::: "memory");   // cur's loads done
        } else {
            asm volatile("s_waitcnt vmcnt(0)" ::: "memory");
        }
        __builtin_amdgcn_sched_barrier(0);
        __builtin_amdgcn_s_barrier();                           // all waves: cur ready
        __builtin_amdgcn_sched_barrier(0);
#pragma unroll
        for (int kk = 0; kk < 2; ++kk) {
            const int kx = kk << 6;  // k-half advances via XOR (bit 6), not add
            bf16x8 bfr[4];
#pragma unroll
            for (int fc = 0; fc < 4; ++fc)
                bfr[fc] = *(const bf16x8*)(lds + cb + (boffs[fc] ^ kx));
#pragma unroll
            for (int fr = 0; fr < 4; ++fr) {
                bf16x8 af = *(const bf16x8*)(lds + cb + (aoffs[fr] ^ kx));
#pragma unroll
                for (int fc = 0; fc < 4; ++fc)
                    acc[fr][fc] = __builtin_amdgcn_mfma_f32_16x16x32_bf16(af, bfr[fc],
                                                                          acc[fr][fc], 0, 0, 0);
            }
        }
        __builtin_amdgcn_s_barrier();                           // all waves done with cur
    }

    float bv[4];
#pragma unroll
    for (int fc = 0; fc < 4; ++fc) bv[fc] = bias[wid * 64 + fc * 16 + lr];

    if (!OUT_BF16) {
        float* out = (float*)outp;
#pragma unroll
        for (int fr = 0; fr < 4; ++fr)
#pragma unroll
            for (int reg = 0; reg < 4; ++reg) {
                int row = bm + fr * 16 + g * 4 + reg;
                if (row < N_NODES) {
#pragma unroll
                    for (int fc = 0; fc < 4; ++fc)
                        out[(size_t)row * 256 + wid * 64 + fc * 16 + lr] =
                            acc[fr][fc][reg] + bv[fc];
                }
            }
    } else {
        ushort* out = (ushort*)outp;
        float (*L)[260] = (float(*)[260])lds;
#pragma unroll 1
        for (int half = 0; half < 2; ++half) {
            __syncthreads();
#pragma unroll
            for (int fr2 = 0; fr2 < 2; ++fr2) {
                int fr = half * 2 + fr2;
#pragma unroll
                for (int fc = 0; fc < 4; ++fc)
#pragma unroll
                    for (int reg = 0; reg < 4; ++reg) {
                        int r = fr2 * 16 + g * 4 + reg;
                        L[r][wid * 64 + fc * 16 + lr] = fmaxf(acc[fr][fc][reg] + bv[fc], 0.f);
                    }
            }
            __syncthreads();
            int r  = tid >> 3;
            int ch = tid & 7;
            int grow = bm + half * 32 + r;
            if (grow < N_NODES) {
#pragma unroll
                for (int q = 0; q < 4; ++q) {
                    float4 u0 = *(const float4*)&L[r][ch * 32 + q * 8];
                    float4 u1 = *(const float4*)&L[r][ch * 32 + q * 8 + 4];
                    uint2 pk;
                    pk.x = (unsigned)f2b(u0.x) | ((unsigned)f2b(u0.y) << 16);
                    pk.y = (unsigned)f2b(u0.z) | ((unsigned)f2b(u0.w) << 16);
                    uint2 pk2;
                    pk2.x = (unsigned)f2b(u1.x) | ((unsigned)f2b(u1.y) << 16);
                    pk2.y = (unsigned)f2b(u1.z) | ((unsigned)f2b(u1.w) << 16);
                    uint4 w4 = make_uint4(pk.x, pk.y, pk2.x, pk2.y);
                    *(uint4*)&out[(size_t)grow * 256 + ch * 32 + q * 8] = w4;
                }
            }
        }
    }
}

extern "C" void kernel_launch(void* const* d_in, const int* in_sizes, int n_in,
                              void* d_out, int out_size, void* d_ws, size_t ws_size,
                              hipStream_t stream) {
    const float* x     = (const float*)d_in[0];
    const int*   erow  = (const int*)d_in[1];
    const int*   ecol  = (const int*)d_in[2];
    const float* evalv = (const float*)d_in[3];
    const float* W1    = (const float*)d_in[4];
    const float* b1    = (const float*)d_in[5];
    const float* Wout  = (const float*)d_in[6];
    const float* bout  = (const float*)d_in[7];
    float* out = (float*)d_out;

    char* ws = (char*)d_ws;
    size_t off = 0;
    auto alloc = [&](size_t bytes) -> void* {
        void* p = ws + off;
        off += (bytes + 255) & ~(size_t)255;
        return p;
    };
    ushort* xb       = (ushort*)alloc((size_t)N_NODES * D * 2);     // 51.2 MB
    ushort* h1b      = (ushort*)alloc((size_t)N_NODES * D * 2);     // 51.2 MB
    ushort* neighb   = (ushort*)alloc((size_t)N_NODES * D * 2);     // 51.2 MB
    ushort* W1t      = (ushort*)alloc((size_t)512 * 256 * 2);
    ushort* Woutt    = (ushort*)alloc((size_t)512 * 256 * 2);
    int*    rowptr   = (int*)alloc((size_t)(N_NODES + 1) * sizeof(int));
    int*    deg      = (int*)alloc((size_t)N_NODES * sizeof(int));
    int*    blocksum = (int*)alloc((size_t)SCAN_BLOCKS * sizeof(int));
    int*    bcursor  = (int*)alloc((size_t)NBUCK * sizeof(int));
    int2*   staging  = (int2*)alloc((size_t)NBUCK * CAP * sizeof(int2));  // 32.1 MB
    int2*   cedge    = (int2*)alloc((size_t)N_EDGES * sizeof(int2));      // 25.6 MB

    // CSR build: binpass1 (fused hist, fixed-slot staging) -> scan -> binpass2
    hipMemsetAsync(deg, 0, (size_t)N_NODES * sizeof(int), stream);
    cursorinit_kernel<<<1, 256, 0, stream>>>(bcursor);
    binpass1_kernel<<<(N_EDGES + EPB - 1) / EPB, 256, 0, stream>>>(erow, ecol, evalv,
                                                                   deg, bcursor, staging);
    scanA_kernel<<<SCAN_BLOCKS, 1024, 0, stream>>>(deg, rowptr, blocksum);
    scanB_kernel<<<1, 64, 0, stream>>>(blocksum, rowptr);
    scanC_kernel<<<SCAN_BLOCKS, 1024, 0, stream>>>(rowptr, blocksum);
    binpass2_kernel<<<NBUCK, 256, 0, stream>>>(rowptr, bcursor, staging, cedge);

    // converts
    cvt_kernel<<<(N_NODES * D / 4 + 255) / 256, 256, 0, stream>>>(x, xb, N_NODES * D / 4);
    wtrans_kernel<<<512, 256, 0, stream>>>(W1, W1t);
    wtrans_kernel<<<512, 256, 0, stream>>>(Wout, Woutt);

    const int gblocks = (N_NODES + 63) / 64;  // 1563
    // layer 1
    spmm_kernel<<<N_NODES / 4, 256, 0, stream>>>(rowptr, cedge, xb, neighb);
    gemm_mfma_kernel<true><<<gblocks, 256, 0, stream>>>(xb, neighb, W1t, b1, h1b);
    // layer 2
    spmm_kernel<<<N_NODES / 4, 256, 0, stream>>>(rowptr, cedge, h1b, neighb);
    gemm_mfma_kernel<false><<<gblocks, 256, 0, stream>>>(h1b, neighb, Woutt, bout, out);
}

// Round 11
// 775.789 us; speedup vs baseline: 1.4089x; 1.0238x over previous
//
#include <hip/hip_runtime.h>
#include <cstddef>
#include <cstdint>

#define N_NODES 100000
#define N_EDGES 3200000
#define D 256
#define BSHIFT 9                                // 512 rows per bucket
#define NBUCK ((N_NODES + (1 << BSHIFT) - 1) >> BSHIFT)  // 196
#define EPB 4096                                // edges per pass-1 block
#define CAP 20480                               // staging slots per bucket (mean 16384 + 32 sigma)

typedef __attribute__((ext_vector_type(8))) short bf16x8;
typedef __attribute__((ext_vector_type(4))) float f32x4;
typedef unsigned int u32;

#define GLOAD16(gsrc, ldst)                                                      \
    __builtin_amdgcn_global_load_lds(                                            \
        (const __attribute__((address_space(1))) void*)(gsrc),                   \
        (__attribute__((address_space(3))) void*)(ldst), 16, 0, 0)

__device__ __forceinline__ ushort f2b(float f) {  // f32 -> bf16 RNE
    unsigned u = __float_as_uint(f);
    return (ushort)((u + 0x7fffu + ((u >> 16) & 1u)) >> 16);
}

// ---------------- bucket cursor init (fixed-capacity slots) ----------------
__global__ void cursorinit_kernel(int* __restrict__ bucket_cursor) {
    int b = blockIdx.x * 256 + threadIdx.x;
    if (b < NBUCK) bucket_cursor[b] = b * CAP;
}

// ---------------- binned scatter pass 1 (no histogram needed anymore) ------------
// Packs (r & 511) into bits 17-25 of the col word; staging slot base = b*CAP.
__global__ __launch_bounds__(256) void binpass1_kernel(const int* __restrict__ erow,
                                                       const int* __restrict__ ecol,
                                                       const float* __restrict__ evalv,
                                                       int* __restrict__ bucket_cursor,
                                                       int2* __restrict__ staging) {
    __shared__ int cnt[NBUCK];
    __shared__ int lstart[NBUCK];
    __shared__ int gbase[NBUCK];
    __shared__ int wtot[4];
    __shared__ int woff[4];
    __shared__ int2 lcv[EPB];            // 32 KB (packed col+row | val)
    __shared__ unsigned char lbb[EPB];   // 4 KB bucket id per staged slot
    const int tid = threadIdx.x;
    const size_t base = (size_t)blockIdx.x * EPB;
    for (int b = tid; b < NBUCK; b += 256) cnt[b] = 0;
    __syncthreads();
    int bb[16];
    int2 pcv[16];
    int loff[16];
#pragma unroll
    for (int i = 0; i < 16; ++i) {
        size_t e = base + (size_t)i * 256 + tid;
        if (e < N_EDGES) {
            int r = erow[e];
            int b = r >> BSHIFT;
            bb[i] = b;
            pcv[i] = make_int2(ecol[e] | ((r & ((1 << BSHIFT) - 1)) << 17),
                               __float_as_int(evalv[e]));
            loff[i] = atomicAdd(&cnt[b], 1);
        } else {
            bb[i] = -1;
        }
    }
    __syncthreads();
    {   // exclusive scan of cnt[0..NBUCK) + claim global staging ranges
        int b = tid;
        int v = (b < NBUCK) ? cnt[b] : 0;
        int lane = tid & 63, wv = tid >> 6;
        int inc = v;
#pragma unroll
        for (int off = 1; off < 64; off <<= 1) {
            int u = __shfl_up(inc, off, 64);
            if (lane >= off) inc += u;
        }
        if (lane == 63) wtot[wv] = inc;
        __syncthreads();
        if (tid == 0) {
            int run = 0;
#pragma unroll
            for (int w = 0; w < 4; ++w) { woff[w] = run; run += wtot[w]; }
        }
        __syncthreads();
        int exc = woff[wv] + inc - v;
        if (b < NBUCK) {
            lstart[b] = exc;
            if (v > 0) gbase[b] = atomicAdd(&bucket_cursor[b], v);
        }
    }
    __syncthreads();
#pragma unroll
    for (int i = 0; i < 16; ++i) {
        if (bb[i] >= 0) {
            int p = lstart[bb[i]] + loff[i];
            lcv[p] = pcv[i];
            lbb[p] = (unsigned char)bb[i];
        }
    }
    __syncthreads();
    const int total = lstart[NBUCK - 1] + cnt[NBUCK - 1];
    for (int p = tid; p < total; p += 256) {
        int b = lbb[p];
        int g = gbase[b] + (p - lstart[b]);
        staging[g] = lcv[p];
    }
}

// ---------------- binned scatter pass 2: count+scan in LDS, emit rowrange --------
// Replaces the global deg histogram + 3 scan kernels: each block counts its
// bucket's 512 rows, scans locally, writes rowrange[r]=(start,end) (absolute
// into the bucket's fixed cedge window), then scatters edges row-grouped.
__global__ __launch_bounds__(256) void binpass2_kernel(const int* __restrict__ bucket_cursor,
                                                       const int2* __restrict__ staging,
                                                       int2* __restrict__ cedge,
                                                       int2* __restrict__ rowrange) {
    __shared__ int cnt[1 << BSHIFT];
    __shared__ int scur[1 << BSHIFT];
    __shared__ int wtot[4];
    __shared__ int woff[4];
    const int b   = blockIdx.x;
    const int tid = threadIdx.x;
    const int base = b * CAP;
    const int hi   = bucket_cursor[b];
    for (int i = tid; i < (1 << BSHIFT); i += 256) cnt[i] = 0;
    __syncthreads();
    for (int k = base + tid; k < hi; k += 256)
        atomicAdd(&cnt[((u32)staging[k].x) >> 17], 1);
    __syncthreads();
    // exclusive scan of 512 counters (2 per thread)
    int v0 = cnt[2 * tid];
    int v1 = cnt[2 * tid + 1];
    int s = v0 + v1;
    int lane = tid & 63, wv = tid >> 6;
    int inc = s;
#pragma unroll
    for (int off = 1; off < 64; off <<= 1) {
        int u = __shfl_up(inc, off, 64);
        if (lane >= off) inc += u;
    }
    if (lane == 63) wtot[wv] = inc;
    __syncthreads();
    if (tid == 0) {
        int run = 0;
#pragma unroll
        for (int w = 0; w < 4; ++w) { woff[w] = run; run += wtot[w]; }
    }
    __syncthreads();
    int exc = woff[wv] + inc - s;
    int g0 = base + exc;
    scur[2 * tid]     = g0;
    scur[2 * tid + 1] = g0 + v0;
    const int r0 = b << BSHIFT;
    int r = r0 + 2 * tid;
    if (r < N_NODES)     rowrange[r]     = make_int2(g0, g0 + v0);
    if (r + 1 < N_NODES) rowrange[r + 1] = make_int2(g0 + v0, g0 + v0 + v1);
    __syncthreads();
    for (int k = base + tid; k < hi; k += 256) {
        int2 e = staging[k];
        int rloc = ((u32)e.x) >> 17;
        int pos = atomicAdd(&scur[rloc], 1);
        cedge[pos] = make_int2(e.x & 0x1FFFF, e.y);
    }
}

// ---------------- f32 -> bf16 elementwise ----------------
__global__ __launch_bounds__(256) void cvt_kernel(const float* __restrict__ in,
                                                  ushort* __restrict__ out, int n4) {
    int i = blockIdx.x * 256 + threadIdx.x;
    if (i < n4) {
        float4 v = ((const float4*)in)[i];
        uint2 p;
        p.x = (unsigned)f2b(v.x) | ((unsigned)f2b(v.y) << 16);
        p.y = (unsigned)f2b(v.z) | ((unsigned)f2b(v.w) << 16);
        ((uint2*)out)[i] = p;
    }
}

// ---------------- both W [512][256] f32 -> Wt [256][512] bf16 (one launch) -------
__global__ __launch_bounds__(256) void wtrans_kernel(const float* __restrict__ W1,
                                                     const float* __restrict__ Wout,
                                                     ushort* __restrict__ W1t,
                                                     ushort* __restrict__ Woutt) {
    int t = blockIdx.x * 256 + threadIdx.x;       // 0..262143
    const float* W = (t < 131072) ? W1 : Wout;
    ushort* Wt     = (t < 131072) ? W1t : Woutt;
    int u = t & 131071;
    int j = u & 255;
    int k = u >> 8;
    Wt[(size_t)j * 512 + k] = f2b(W[(size_t)k * 256 + j]);
}

// ---------------- CSR SpMM (bf16 features): one wave per node (R6-proven) ---------
__global__ __launch_bounds__(256) void spmm_kernel(const int2* __restrict__ rowrange,
                                                   const int2* __restrict__ cedge,
                                                   const ushort* __restrict__ h,
                                                   ushort* __restrict__ outb) {
    const int node = (blockIdx.x << 2) + (threadIdx.x >> 6);
    const int lane = threadIdx.x & 63;
    const uint2* __restrict__ h2 = (const uint2*)h;
    int2 rr = rowrange[node];
    int k = rr.x;
    const int end = rr.y;
    float a0 = 0.f, a1 = 0.f, a2 = 0.f, a3 = 0.f;
#define EDGE_FMA(e, d)                                              \
    {                                                               \
        float v = __int_as_float((e).y);                            \
        a0 = fmaf(v, __uint_as_float((d).x << 16), a0);             \
        a1 = fmaf(v, __uint_as_float((d).x & 0xffff0000u), a1);     \
        a2 = fmaf(v, __uint_as_float((d).y << 16), a2);             \
        a3 = fmaf(v, __uint_as_float((d).y & 0xffff0000u), a3);     \
    }
    for (; k + 4 <= end; k += 4) {
        int2 e0 = cedge[k];
        int2 e1 = cedge[k + 1];
        int2 e2 = cedge[k + 2];
        int2 e3 = cedge[k + 3];
        uint2 d0 = h2[(size_t)e0.x * 64 + lane];
        uint2 d1 = h2[(size_t)e1.x * 64 + lane];
        uint2 d2 = h2[(size_t)e2.x * 64 + lane];
        uint2 d3 = h2[(size_t)e3.x * 64 + lane];
        EDGE_FMA(e0, d0)
        EDGE_FMA(e1, d1)
        EDGE_FMA(e2, d2)
        EDGE_FMA(e3, d3)
    }
    for (; k < end; ++k) {
        int2 e = cedge[k];
        uint2 d = h2[(size_t)e.x * 64 + lane];
        EDGE_FMA(e, d)
    }
#undef EDGE_FMA
    uint2 p;
    p.x = (unsigned)f2b(a0) | ((unsigned)f2b(a1) << 16);
    p.y = (unsigned)f2b(a2) | ((unsigned)f2b(a3) << 16);
    ((uint2*)outb)[(size_t)node * 64 + lane] = p;
}

// ---------------- MFMA concat-GEMM: BK=32, chunk-major LDS, 4 blocks/CU ----------
// Tile 20KB (A 4KB + B 16KB), double-buffered = 40KB -> 4 blocks/CU (160KB exact).
// Chunk-major layout: A byte = chunk*1024 + row*16 (chunk=k/8 in tile, row 0..63);
// B byte = 4096 + chunk*4096 + n*16 (n = output col 0..255). Frag ds_read_b128
// granule = lr mod 8 -> uniform 8 lanes/granule = the b128 floor, no swizzle.
// Staging is gload_lds-linear: 1 A-slot + 4 B-slots per wave per t, vmcnt(5).
#define STAGE_TILE(bufbase, tt)                                                  \
    {                                                                            \
        const ushort* Ab_ = ((tt) < 8) ? A1 : A2;                                \
        const int k0_ = ((tt) & 7) * 32;                                         \
        GLOAD16(Ab_ + (size_t)rowA * 256 + k0_ + wid * 8,                        \
                lds + (bufbase) + wid * 1024);                                   \
        _Pragma("unroll")                                                        \
        for (int p = 0; p < 4; ++p)                                              \
            GLOAD16(wBsrc + (tt) * 32 + p * 8,                                   \
                    lds + (bufbase) + 4096 + (p * 4 + wid) * 1024);              \
    }

template <bool OUT_BF16>
__global__ __launch_bounds__(256, 4) void gemm_mfma_kernel(const ushort* __restrict__ A1,
                                                           const ushort* __restrict__ A2,
                                                           const ushort* __restrict__ Wt,
                                                           const float* __restrict__ bias,
                                                           void* __restrict__ outp) {
    __shared__ __align__(16) char lds[40960];  // 2 x (A 4KB + B 16KB)
    const int tid  = threadIdx.x;
    const int wid  = tid >> 6;
    const int lane = tid & 63;
    const int lr   = lane & 15;
    const int g    = lane >> 4;
    const int bm   = blockIdx.x * 64;

    // staging sources (linear LDS dest = base + lane*16)
    int rowA = bm + lane;                        // A: slot wid = chunk wid, lane = row
    if (rowA >= N_NODES) rowA = N_NODES - 1;     // clamp (stores guarded)
    const ushort* wBsrc = Wt + ((size_t)(wid * 64 + lane) << 9);  // + t*32 + p*8

    // frag read offsets (chunk-major, conflict-floor)
    int aoff[4], boff[4];
#pragma unroll
    for (int f = 0; f < 4; ++f) {
        aoff[f] = g * 1024 + (f * 16 + lr) * 16;
        boff[f] = 4096 + g * 4096 + (wid * 64 + f * 16 + lr) * 16;
    }

    f32x4 acc[4][4];
#pragma unroll
    for (int i = 0; i < 4; ++i)
#pragma unroll
        for (int j = 0; j < 4; ++j) acc[i][j] = (f32x4){0.f, 0.f, 0.f, 0.f};

    STAGE_TILE(0, 0);  // prologue: tile 0 into buf 0

#pragma unroll 1
    for (int t = 0; t < 16; ++t) {
        const int cb = (t & 1) * 20480;
        if (t < 15) {
            STAGE_TILE(20480 - cb, t + 1);                      // next tile -> other buf
            asm volatile("s_waitcnt vmcnt(5)" ::: "memory");    // cur's 5 loads done
        } else {
            asm volatile("s_waitcnt vmcnt(0)" ::: "memory");
        }
        __builtin_amdgcn_sched_barrier(0);
        __builtin_amdgcn_s_barrier();                           // all waves: cur ready
        __builtin_amdgcn_sched_barrier(0);
        bf16x8 bfr[4];
#pragma unroll
        for (int fc = 0; fc < 4; ++fc)
            bfr[fc] = *(const bf16x8*)(lds + cb + boff[fc]);
#pragma unroll
        for (int fr = 0; fr < 4; ++fr) {
            bf16x8 af = *(const bf16x8*)(lds + cb + aoff[fr]);
#pragma unroll
            for (int fc = 0; fc < 4; ++fc)
                acc[fr][fc] = __builtin_amdgcn_mfma_f32_16x16x32_bf16(af, bfr[fc],
                                                                      acc[fr][fc], 0, 0, 0);
        }
        __builtin_amdgcn_s_barrier();                           // all waves done with cur
    }

    float bv[4];
#pragma unroll
    for (int fc = 0; fc < 4; ++fc) bv[fc] = bias[wid * 64 + fc * 16 + lr];

    if (!OUT_BF16) {
        float* out = (float*)outp;
#pragma unroll
        for (int fr = 0; fr < 4; ++fr)
#pragma unroll
            for (int reg = 0; reg < 4; ++reg) {
                int row = bm + fr * 16 + g * 4 + reg;
                if (row < N_NODES) {
#pragma unroll
                    for (int fc = 0; fc < 4; ++fc)
                        out[(size_t)row * 256 + wid * 64 + fc * 16 + lr] =
                            acc[fr][fc][reg] + bv[fc];
                }
            }
    } else {
        ushort* out = (ushort*)outp;
        float (*L)[260] = (float(*)[260])lds;
#pragma unroll 1
        for (int half = 0; half < 2; ++half) {
            __syncthreads();
#pragma unroll
            for (int fr2 = 0; fr2 < 2; ++fr2) {
                int fr = half * 2 + fr2;
#pragma unroll
                for (int fc = 0; fc < 4; ++fc)
#pragma unroll
                    for (int reg = 0; reg < 4; ++reg) {
                        int r = fr2 * 16 + g * 4 + reg;
                        L[r][wid * 64 + fc * 16 + lr] = fmaxf(acc[fr][fc][reg] + bv[fc], 0.f);
                    }
            }
            __syncthreads();
            int r  = tid >> 3;
            int ch = tid & 7;
            int grow = bm + half * 32 + r;
            if (grow < N_NODES) {
#pragma unroll
                for (int q = 0; q < 4; ++q) {
                    float4 u0 = *(const float4*)&L[r][ch * 32 + q * 8];
                    float4 u1 = *(const float4*)&L[r][ch * 32 + q * 8 + 4];
                    uint2 pk;
                    pk.x = (unsigned)f2b(u0.x) | ((unsigned)f2b(u0.y) << 16);
                    pk.y = (unsigned)f2b(u0.z) | ((unsigned)f2b(u0.w) << 16);
                    uint2 pk2;
                    pk2.x = (unsigned)f2b(u1.x) | ((unsigned)f2b(u1.y) << 16);
                    pk2.y = (unsigned)f2b(u1.z) | ((unsigned)f2b(u1.w) << 16);
                    uint4 w4 = make_uint4(pk.x, pk.y, pk2.x, pk2.y);
                    *(uint4*)&out[(size_t)grow * 256 + ch * 32 + q * 8] = w4;
                }
            }
        }
    }
}

extern "C" void kernel_launch(void* const* d_in, const int* in_sizes, int n_in,
                              void* d_out, int out_size, void* d_ws, size_t ws_size,
                              hipStream_t stream) {
    const float* x     = (const float*)d_in[0];
    const int*   erow  = (const int*)d_in[1];
    const int*   ecol  = (const int*)d_in[2];
    const float* evalv = (const float*)d_in[3];
    const float* W1    = (const float*)d_in[4];
    const float* b1    = (const float*)d_in[5];
    const float* Wout  = (const float*)d_in[6];
    const float* bout  = (const float*)d_in[7];
    float* out = (float*)d_out;

    char* ws = (char*)d_ws;
    size_t off = 0;
    auto alloc = [&](size_t bytes) -> void* {
        void* p = ws + off;
        off += (bytes + 255) & ~(size_t)255;
        return p;
    };
    ushort* xb       = (ushort*)alloc((size_t)N_NODES * D * 2);     // 51.2 MB
    ushort* h1b      = (ushort*)alloc((size_t)N_NODES * D * 2);     // 51.2 MB
    ushort* neighb   = (ushort*)alloc((size_t)N_NODES * D * 2);     // 51.2 MB
    ushort* W1t      = (ushort*)alloc((size_t)512 * 256 * 2);
    ushort* Woutt    = (ushort*)alloc((size_t)512 * 256 * 2);
    int*    bcursor  = (int*)alloc((size_t)NBUCK * sizeof(int));
    int2*   rowrange = (int2*)alloc((size_t)N_NODES * sizeof(int2));      // 0.8 MB
    int2*   staging  = (int2*)alloc((size_t)NBUCK * CAP * sizeof(int2));  // 32.1 MB
    int2*   cedge    = (int2*)alloc((size_t)NBUCK * CAP * sizeof(int2));  // 32.1 MB

    // CSR build: binpass1 (bucket staging) -> binpass2 (count/scan/rowrange/scatter)
    cursorinit_kernel<<<1, 256, 0, stream>>>(bcursor);
    binpass1_kernel<<<(N_EDGES + EPB - 1) / EPB, 256, 0, stream>>>(erow, ecol, evalv,
                                                                   bcursor, staging);
    binpass2_kernel<<<NBUCK, 256, 0, stream>>>(bcursor, staging, cedge, rowrange);

    // converts
    cvt_kernel<<<(N_NODES * D / 4 + 255) / 256, 256, 0, stream>>>(x, xb, N_NODES * D / 4);
    wtrans_kernel<<<1024, 256, 0, stream>>>(W1, Wout, W1t, Woutt);

    const int gblocks = (N_NODES + 63) / 64;  // 1563
    // layer 1
    spmm_kernel<<<N_NODES / 4, 256, 0, stream>>>(rowrange, cedge, xb, neighb);
    gemm_mfma_kernel<true><<<gblocks, 256, 0, stream>>>(xb, neighb, W1t, b1, h1b);
    // layer 2
    spmm_kernel<<<N_NODES / 4, 256, 0, stream>>>(rowrange, cedge, h1b, neighb);
    gemm_mfma_kernel<false><<<gblocks, 256, 0, stream>>>(h1b, neighb, Woutt, bout, out);
}